// Round 1
// baseline (334.812 us; speedup 1.0000x reference)
//
#include <hip/hip_runtime.h>
#include <math.h>

#define Bsz 8
#define Nn 1024
#define Ff 512
#define Hh 4
#define Dd 128

// ---------------- Kernel 1: h = x @ W  (C[8192,512] = X[8192,512] @ W[512,512]) ----------------
__global__ __launch_bounds__(256) void gemm_xw(const float* __restrict__ X,
                                               const float* __restrict__ Wm,
                                               float* __restrict__ Hb) {
    __shared__ float Xs[16][68];   // [k][m], padded so float4 reads stay 16B-aligned (68*4=272=16*17)
    __shared__ float Ws[16][64];   // [k][n]
    const int bm = blockIdx.y * 64;
    const int bn = blockIdx.x * 64;
    const int tid = threadIdx.x;
    const int tx = tid % 16, ty = tid / 16;
    float acc[4][4];
    #pragma unroll
    for (int i = 0; i < 4; ++i)
        #pragma unroll
        for (int j = 0; j < 4; ++j) acc[i][j] = 0.f;

    const int xRow = tid / 4;           // 0..63
    const int xK   = (tid % 4) * 4;     // 0,4,8,12
    const int wRow = tid / 16;          // 0..15
    const int wCol = (tid % 16) * 4;    // 0..60

    for (int k0 = 0; k0 < Ff; k0 += 16) {
        float4 xv = *(const float4*)(X + (size_t)(bm + xRow) * Ff + k0 + xK);
        *(float4*)(&Ws[wRow][wCol]) = *(const float4*)(Wm + (size_t)(k0 + wRow) * Ff + bn + wCol);
        Xs[xK + 0][xRow] = xv.x;
        Xs[xK + 1][xRow] = xv.y;
        Xs[xK + 2][xRow] = xv.z;
        Xs[xK + 3][xRow] = xv.w;
        __syncthreads();
        #pragma unroll
        for (int k = 0; k < 16; ++k) {
            float4 a  = *(const float4*)(&Xs[k][ty * 4]);
            float4 bv = *(const float4*)(&Ws[k][tx * 4]);
            float am[4] = {a.x, a.y, a.z, a.w};
            float bb[4] = {bv.x, bv.y, bv.z, bv.w};
            #pragma unroll
            for (int i = 0; i < 4; ++i)
                #pragma unroll
                for (int j = 0; j < 4; ++j)
                    acc[i][j] += am[i] * bb[j];
        }
        __syncthreads();
    }
    #pragma unroll
    for (int i = 0; i < 4; ++i) {
        float4 o = {acc[i][0], acc[i][1], acc[i][2], acc[i][3]};
        *(float4*)(Hb + (size_t)(bm + ty * 4 + i) * Ff + bn + tx * 4) = o;
    }
}

// ---------------- Kernel 2: e_i[b,h,n], e_j[b,h,n] ----------------
__global__ __launch_bounds__(64) void eij_kernel(const float* __restrict__ Hb,
                                                 const float* __restrict__ a_src,
                                                 const float* __restrict__ a_dst,
                                                 float* __restrict__ ei,
                                                 float* __restrict__ ej) {
    const int bn = blockIdx.x;            // b*1024 + n
    const int lane = threadIdx.x;         // 0..63
    const int b = bn >> 10, n = bn & 1023;
    const float* hrow = Hb + (size_t)bn * Ff;
    #pragma unroll
    for (int h = 0; h < Hh; ++h) {
        float h0 = hrow[h * 128 + lane];
        float h1 = hrow[h * 128 + 64 + lane];
        float v1 = h0 * a_src[h * 128 + lane] + h1 * a_src[h * 128 + 64 + lane];
        float v2 = h0 * a_dst[h * 128 + lane] + h1 * a_dst[h * 128 + 64 + lane];
        #pragma unroll
        for (int off = 32; off > 0; off >>= 1) {
            v1 += __shfl_down(v1, off);
            v2 += __shfl_down(v2, off);
        }
        if (lane == 0) {
            ei[(b * Hh + h) * Nn + n] = v1;
            ej[(b * Hh + h) * Nn + n] = v2;
        }
    }
}

// ---------------- Kernel 3: masked softmax + attn@h + residual + LayerNorm ----------------
// Block: 256 threads = 4 waves. Each block: batch b, 16 rows i. Wave ig owns rows i0+ig*4 .. +3.
// Thread (tx within wave) owns 8 contiguous f = tx*8..tx*8+7 (all in head tx/16).
__global__ __launch_bounds__(256) void attn_kernel(const float* __restrict__ Hb,
                                                   const float* __restrict__ X,
                                                   const int*   __restrict__ mask,
                                                   const float* __restrict__ ei,
                                                   const float* __restrict__ ej,
                                                   const float* __restrict__ gamma,
                                                   const float* __restrict__ beta,
                                                   float* __restrict__ out) {
    __shared__ float s_ej[Hh][Nn];        // 16 KB
    __shared__ float s_mj[Nn];            // 4 KB
    __shared__ float s_ei[Hh][16];
    __shared__ float s_mi[16];
    __shared__ float s_m[Hh][16];
    __shared__ float s_rs[Hh][16];
    __shared__ float s_w[Hh][128][16];    // 32 KB  [h][jj][i] -> b128 reads of 4 consecutive i

    const int b  = blockIdx.y;
    const int i0 = blockIdx.x * 16;
    const int tid = threadIdx.x;
    const int tx = tid & 63, ig = tid >> 6;

    // phase 0: stage e_j, mask, e_i, mask_i
    #pragma unroll
    for (int k = 0; k < 16; ++k) {
        int idx = tid + 256 * k;          // 0..4095
        int h = idx >> 10, j = idx & 1023;
        s_ej[h][j] = ej[(b * Hh + h) * Nn + j];
    }
    #pragma unroll
    for (int k = 0; k < 4; ++k) {
        int j = tid + 256 * k;
        s_mj[j] = (float)mask[b * Nn + j];
    }
    if (tid < 64) {
        int h = tid >> 4, il = tid & 15;
        s_ei[h][il] = ei[(b * Hh + h) * Nn + i0 + il];
    }
    if (tid < 16) s_mi[tid] = (float)mask[b * Nn + i0 + tid];
    __syncthreads();

    // phase 1: per (h, i) row max and sum of exp
    {
        int p = tid >> 2, sub = tid & 3;  // 64 pairs, 4 threads each
        int il = p & 15, h = p >> 4;
        float eiv = s_ei[h][il];
        float mi  = s_mi[il];
        float mx = -3.0e38f;
        for (int j = sub; j < Nn; j += 4) {
            float t = eiv + s_ej[h][j];
            float l = t > 0.f ? t : 0.2f * t;
            float lg = (mi * s_mj[j]) != 0.f ? l : -1e9f;
            mx = fmaxf(mx, lg);
        }
        mx = fmaxf(mx, __shfl_xor(mx, 1));
        mx = fmaxf(mx, __shfl_xor(mx, 2));
        float s = 0.f;
        for (int j = sub; j < Nn; j += 4) {
            float t = eiv + s_ej[h][j];
            float l = t > 0.f ? t : 0.2f * t;
            float lg = (mi * s_mj[j]) != 0.f ? l : -1e9f;
            s += __expf(lg - mx);
        }
        s += __shfl_xor(s, 1);
        s += __shfl_xor(s, 2);
        if (sub == 0) { s_m[h][il] = mx; s_rs[h][il] = 1.f / s; }
    }
    __syncthreads();

    // phase 2: weighted sum over j in 8 tiles of 128
    const int ht = tx >> 4;               // head of this thread's f-range
    float acc[4][8];
    #pragma unroll
    for (int q = 0; q < 4; ++q)
        #pragma unroll
        for (int r = 0; r < 8; ++r) acc[q][r] = 0.f;

    for (int t8 = 0; t8 < 8; ++t8) {
        const int j0 = t8 * 128;
        // 2a: materialize normalized weights for this tile
        #pragma unroll
        for (int k = 0; k < 32; ++k) {
            int e  = tid + 256 * k;       // 0..8191
            int il = e & 15;
            int jj = (e >> 4) & 127;
            int h  = e >> 11;
            float eiv = s_ei[h][il], mi = s_mi[il];
            float t = eiv + s_ej[h][j0 + jj];
            float l = t > 0.f ? t : 0.2f * t;
            float lg = (mi * s_mj[j0 + jj]) != 0.f ? l : -1e9f;
            s_w[h][jj][il] = __expf(lg - s_m[h][il]) * s_rs[h][il];
        }
        __syncthreads();
        // 2b: accumulate
        const float* hb = Hb + ((size_t)(b * Nn + j0)) * Ff + tx * 8;
        for (int jj = 0; jj < 128; ++jj) {
            float4 a = *(const float4*)(hb + (size_t)jj * Ff);
            float4 c = *(const float4*)(hb + (size_t)jj * Ff + 4);
            float4 wv = *(const float4*)(&s_w[ht][jj][ig * 4]);
            float wq[4] = {wv.x, wv.y, wv.z, wv.w};
            #pragma unroll
            for (int q = 0; q < 4; ++q) {
                acc[q][0] += wq[q] * a.x; acc[q][1] += wq[q] * a.y;
                acc[q][2] += wq[q] * a.z; acc[q][3] += wq[q] * a.w;
                acc[q][4] += wq[q] * c.x; acc[q][5] += wq[q] * c.y;
                acc[q][6] += wq[q] * c.z; acc[q][7] += wq[q] * c.w;
            }
        }
        __syncthreads();
    }

    // epilogue: residual + LayerNorm per row (each wave owns 4 rows; 64 lanes x 8 f = 512)
    #pragma unroll
    for (int q = 0; q < 4; ++q) {
        const int i = i0 + ig * 4 + q;
        const float* xp = X + ((size_t)(b * Nn + i)) * Ff + tx * 8;
        float4 xa = *(const float4*)(xp);
        float4 xc = *(const float4*)(xp + 4);
        float v[8];
        v[0] = acc[q][0] + xa.x; v[1] = acc[q][1] + xa.y;
        v[2] = acc[q][2] + xa.z; v[3] = acc[q][3] + xa.w;
        v[4] = acc[q][4] + xc.x; v[5] = acc[q][5] + xc.y;
        v[6] = acc[q][6] + xc.z; v[7] = acc[q][7] + xc.w;
        float s1 = 0.f, s2 = 0.f;
        #pragma unroll
        for (int r = 0; r < 8; ++r) { s1 += v[r]; s2 += v[r] * v[r]; }
        #pragma unroll
        for (int off = 32; off > 0; off >>= 1) {
            s1 += __shfl_xor(s1, off);
            s2 += __shfl_xor(s2, off);
        }
        const float mean = s1 * (1.f / 512.f);
        const float var  = s2 * (1.f / 512.f) - mean * mean;
        const float rstd = rsqrtf(var + 1e-5f);
        const int f0 = tx * 8;
        float* op = out + ((size_t)(b * Nn + i)) * Ff + f0;
        float4 o1, o2;
        o1.x = (v[0] - mean) * rstd * gamma[f0 + 0] + beta[f0 + 0];
        o1.y = (v[1] - mean) * rstd * gamma[f0 + 1] + beta[f0 + 1];
        o1.z = (v[2] - mean) * rstd * gamma[f0 + 2] + beta[f0 + 2];
        o1.w = (v[3] - mean) * rstd * gamma[f0 + 3] + beta[f0 + 3];
        o2.x = (v[4] - mean) * rstd * gamma[f0 + 4] + beta[f0 + 4];
        o2.y = (v[5] - mean) * rstd * gamma[f0 + 5] + beta[f0 + 5];
        o2.z = (v[6] - mean) * rstd * gamma[f0 + 6] + beta[f0 + 6];
        o2.w = (v[7] - mean) * rstd * gamma[f0 + 7] + beta[f0 + 7];
        *(float4*)op = o1;
        *(float4*)(op + 4) = o2;
    }
}

extern "C" void kernel_launch(void* const* d_in, const int* in_sizes, int n_in,
                              void* d_out, int out_size, void* d_ws, size_t ws_size,
                              hipStream_t stream) {
    const float* x     = (const float*)d_in[0];
    const int*   mask  = (const int*)d_in[1];
    const float* W     = (const float*)d_in[2];
    const float* a_src = (const float*)d_in[3];
    const float* a_dst = (const float*)d_in[4];
    const float* gamma = (const float*)d_in[5];
    const float* beta  = (const float*)d_in[6];
    float* out = (float*)d_out;

    float* hbuf = (float*)d_ws;                       // 8*1024*512 floats = 16 MB
    float* ei   = hbuf + (size_t)Bsz * Nn * Ff;       // 8*4*1024
    float* ej   = ei + (size_t)Bsz * Hh * Nn;         // 8*4*1024

    gemm_xw<<<dim3(8, 128), 256, 0, stream>>>(x, W, hbuf);
    eij_kernel<<<dim3(Bsz * Nn), 64, 0, stream>>>(hbuf, a_src, a_dst, ei, ej);
    attn_kernel<<<dim3(64, Bsz), 256, 0, stream>>>(hbuf, x, mask, ei, ej, gamma, beta, out);
}

// Round 2
// 179.477 us; speedup vs baseline: 1.8655x; 1.8655x over previous
//
#include <hip/hip_runtime.h>
#include <math.h>

#define Bsz 8
#define Nn 1024
#define Ff 512
#define Hh 4
#define Dd 128

typedef float f32x4 __attribute__((ext_vector_type(4)));
typedef short bf16x8 __attribute__((ext_vector_type(8)));

__device__ inline uint f2b1(float a) {
    union { float f; uint u; } v; v.f = a;
    return (v.u + 0x7fffu + ((v.u >> 16) & 1u)) >> 16;   // RNE f32->bf16
}
__device__ inline uint f2b_pk(float a, float b) { return f2b1(a) | (f2b1(b) << 16); }
__device__ inline float b2f(ushort u) {
    union { uint u; float f; } v; v.u = ((uint)u) << 16; return v.f;
}

// ============ Kernel 1: hT[b*512+hd][n] (bf16) = (x @ W)^T, MFMA bf16 ============
// Block 256 thr = 4 waves (2x2 of 64x64), block tile 128(m) x 128(n), K-step 32.
__global__ __launch_bounds__(256) void gemm_xw(const float* __restrict__ X,
                                               const float* __restrict__ Wm,
                                               ushort* __restrict__ hT) {
    __shared__ ushort Asl[4096];   // frag-major: [(m>>4)*4 + (k>>3)][(m&15)*8 + (k&7)]
    __shared__ ushort Bsl[4096];   // frag-major: [(n>>4)*4 + (k>>3)][(n&15)*8 + (k&7)]
    const int tid = threadIdx.x;
    const int bm = blockIdx.y * 128;
    const int bn = blockIdx.x * 128;
    const int w = tid >> 6, lane = tid & 63, quad = lane >> 4, l16 = lane & 15;
    const int wm = (w & 1) * 64, wn = (w >> 1) * 64;

    f32x4 z = {0.f, 0.f, 0.f, 0.f};
    f32x4 acc[4][4];
    #pragma unroll
    for (int i = 0; i < 4; ++i)
        #pragma unroll
        for (int j = 0; j < 4; ++j) acc[i][j] = z;

    const int am = tid >> 1, akh = (tid & 1) * 16;     // A: row am, k-half akh
    const int bkp = tid >> 4, bnc = (tid & 15) * 8;    // B: k-pair 2*bkp, n-chunk bnc

    for (int k0 = 0; k0 < Ff; k0 += 32) {
        // stage A (128 x 32 fp32 -> bf16 frag-major)
        const float4* xp = (const float4*)(X + (size_t)(bm + am) * Ff + k0 + akh);
        float4 f0 = xp[0], f1 = xp[1], f2 = xp[2], f3 = xp[3];
        int kb = akh >> 3;
        uint4 w0 = { f2b_pk(f0.x, f0.y), f2b_pk(f0.z, f0.w), f2b_pk(f1.x, f1.y), f2b_pk(f1.z, f1.w) };
        uint4 w1 = { f2b_pk(f2.x, f2.y), f2b_pk(f2.z, f2.w), f2b_pk(f3.x, f3.y), f2b_pk(f3.z, f3.w) };
        *(uint4*)(&Asl[((am >> 4) * 4 + kb) * 128 + (am & 15) * 8]) = w0;
        *(uint4*)(&Asl[((am >> 4) * 4 + kb + 1) * 128 + (am & 15) * 8]) = w1;
        // stage B (32 x 128 fp32 -> bf16 frag-major, transposing k-pairs into j-pairs)
        const float* wp = Wm + (size_t)(k0 + bkp * 2) * Ff + bn + bnc;
        float4 r0a = *(const float4*)(wp),       r0b = *(const float4*)(wp + 4);
        float4 r1a = *(const float4*)(wp + Ff),  r1b = *(const float4*)(wp + Ff + 4);
        float r0[8] = {r0a.x, r0a.y, r0a.z, r0a.w, r0b.x, r0b.y, r0b.z, r0b.w};
        float r1[8] = {r1a.x, r1a.y, r1a.z, r1a.w, r1b.x, r1b.y, r1b.z, r1b.w};
        #pragma unroll
        for (int n = 0; n < 8; ++n) {
            int nl = bnc + n;
            int el = ((nl >> 4) * 4 + (bkp >> 2)) * 128 + (nl & 15) * 8 + (bkp & 3) * 2;
            ((uint*)Bsl)[el >> 1] = f2b_pk(r0[n], r1[n]);
        }
        __syncthreads();
        bf16x8 a[4], bb[4];
        #pragma unroll
        for (int mt = 0; mt < 4; ++mt)
            a[mt] = *(const bf16x8*)(&Asl[(((wm >> 4) + mt) * 4 + quad) * 128 + l16 * 8]);
        #pragma unroll
        for (int nt = 0; nt < 4; ++nt)
            bb[nt] = *(const bf16x8*)(&Bsl[(((wn >> 4) + nt) * 4 + quad) * 128 + l16 * 8]);
        #pragma unroll
        for (int mt = 0; mt < 4; ++mt)
            #pragma unroll
            for (int nt = 0; nt < 4; ++nt)
                acc[mt][nt] = __builtin_amdgcn_mfma_f32_16x16x32_bf16(a[mt], bb[nt], acc[mt][nt], 0, 0, 0);
        __syncthreads();
    }
    // epilogue: C[m][hd] -> hT[b*512+hd][nseq] bf16 (4 consecutive m packed per store)
    #pragma unroll
    for (int mt = 0; mt < 4; ++mt) {
        int mrow = bm + wm + mt * 16 + quad * 4;
        int bb_ = mrow >> 10, nseq = mrow & 1023;
        #pragma unroll
        for (int nt = 0; nt < 4; ++nt) {
            int hd = bn + wn + nt * 16 + l16;
            uint2 pv;
            pv.x = f2b_pk(acc[mt][nt][0], acc[mt][nt][1]);
            pv.y = f2b_pk(acc[mt][nt][2], acc[mt][nt][3]);
            *(uint2*)(hT + (((size_t)(bb_ * 512 + hd)) << 10) + nseq) = pv;
        }
    }
}

// ============ Kernel 2: e_i / e_j from hT ============
// Grid (32 n-chunks, 8 b); block 256: 8 d-subranges x 32 n, partials reduced in LDS.
__global__ __launch_bounds__(256) void eij_kernel(const ushort* __restrict__ hT,
                                                  const float* __restrict__ a_src,
                                                  const float* __restrict__ a_dst,
                                                  float* __restrict__ ei,
                                                  float* __restrict__ ej) {
    __shared__ float sp1[8][4][32];
    __shared__ float sp2[8][4][32];
    const int b = blockIdx.y;
    const int n0 = blockIdx.x * 32;
    const int tid = threadIdx.x;
    const int w = tid >> 6, lane = tid & 63;
    const int nl = lane & 31, ds = lane >> 5;
    const int wd = w * 2 + ds;   // d-range wd*16 .. +15
    #pragma unroll
    for (int h = 0; h < 4; ++h) {
        float s1 = 0.f, s2 = 0.f;
        const ushort* hp = hT + (((size_t)(b * 512 + h * 128 + wd * 16)) << 10) + n0 + nl;
        #pragma unroll
        for (int dd = 0; dd < 16; ++dd) {
            float v = b2f(hp[(size_t)dd << 10]);
            int d = wd * 16 + dd;
            s1 += v * a_src[h * 128 + d];
            s2 += v * a_dst[h * 128 + d];
        }
        sp1[wd][h][nl] = s1;
        sp2[wd][h][nl] = s2;
    }
    __syncthreads();
    if (tid < 128) {
        int h = tid >> 5, n = tid & 31;
        float s1 = 0.f, s2 = 0.f;
        #pragma unroll
        for (int k = 0; k < 8; ++k) { s1 += sp1[k][h][n]; s2 += sp2[k][h][n]; }
        ei[((b * 4 + h) << 10) + n0 + n] = s1;
        ej[((b * 4 + h) << 10) + n0 + n] = s2;
    }
}

// ============ Kernel 3: weights (exp, un-normalized) -> MFMA PV + ones-MFMA rowsum
//              -> normalize + residual + LayerNorm ============
// Grid (32 i-blocks, 8 b); block 256 = 4 waves, wave w = head w. 32 i-rows/block.
__global__ __launch_bounds__(256) void attn_pv(const ushort* __restrict__ hT,
                                               const float* __restrict__ ei_g,
                                               const float* __restrict__ ej_g,
                                               const int* __restrict__ mask,
                                               const float* __restrict__ X,
                                               const float* __restrict__ gamma,
                                               const float* __restrict__ beta,
                                               float* __restrict__ out) {
    __shared__ ushort s_w[2][4096];   // double-buffered A-frags: el(h,i,jl)
    __shared__ float s_ep[16 * 520];  // epilogue tile [16 rows][512 f], stride 520
    __shared__ float s_maxej[4];
    __shared__ float s_sum[4][33];

    const int b = blockIdx.y, i0 = blockIdx.x * 32;
    const int tid = threadIdx.x;
    const int w = tid >> 6, lane = tid & 63, quad = lane >> 4, l16 = lane & 15;

    // max_j e_j per head (upper bound for softmax shift; exactness preserved)
    {
        const float* ejp = ej_g + ((b * 4 + w) << 10);
        float m = -3.0e38f;
        #pragma unroll
        for (int k = 0; k < 16; ++k) m = fmaxf(m, ejp[lane + 64 * k]);
        #pragma unroll
        for (int off = 1; off < 64; off <<= 1) m = fmaxf(m, __shfl_xor(m, off));
        if (lane == 0) s_maxej[w] = m;
    }
    __syncthreads();

    // weight-producer role: thread owns (head wh, row wi), j-half wjh
    const int wi = tid & 31, wh = (tid >> 5) & 3, wjh = tid >> 7;
    const float ei_r = ei_g[((b * 4 + wh) << 10) + i0 + wi];
    const int mi_r = mask[(b << 10) + i0 + wi];
    float m_r;
    { float t = ei_r + s_maxej[wh]; m_r = mi_r ? fmaxf(t, 0.2f * t) : -1e9f; }

    f32x4 z = {0.f, 0.f, 0.f, 0.f};
    f32x4 acc[2][8], asum[2];
    #pragma unroll
    for (int it = 0; it < 2; ++it) { asum[it] = z;
        #pragma unroll
        for (int dt = 0; dt < 8; ++dt) acc[it][dt] = z; }
    bf16x8 ones;
    #pragma unroll
    for (int q = 0; q < 8; ++q) ones[q] = (short)0x3F80;  // bf16 1.0

    const float* ejh = ej_g + ((b * 4 + wh) << 10);
    const int* mkb = mask + (b << 10);
    const int webase = ((wh * 2 + (wi >> 4)) * 4) * 128 + (wi & 15) * 8;
    const ushort* hTb = hT + (((size_t)(b * 512 + w * 128)) << 10);

    for (int r = 0; r < 32; ++r) {
        const int j0 = r * 32;
        uint* wdst = (uint*)s_w[r & 1];
        #pragma unroll
        for (int g = 0; g < 2; ++g) {
            int jlb = wjh * 16 + g * 8;
            int jg = j0 + jlb;
            float4 e0 = *(const float4*)(ejh + jg);
            float4 e1 = *(const float4*)(ejh + jg + 4);
            int4 q0 = *(const int4*)(mkb + jg);
            int4 q1 = *(const int4*)(mkb + jg + 4);
            float ev[8] = {e0.x, e0.y, e0.z, e0.w, e1.x, e1.y, e1.z, e1.w};
            int   mv[8] = {q0.x, q0.y, q0.z, q0.w, q1.x, q1.y, q1.z, q1.w};
            float wv[8];
            #pragma unroll
            for (int u = 0; u < 8; ++u) {
                float t = ei_r + ev[u];
                float l = fmaxf(t, 0.2f * t);             // leaky_relu 0.2
                float lg = (mi_r && mv[u]) ? l : -1e9f;
                wv[u] = __expf(lg - m_r);                 // un-normalized weight
            }
            int wordbase = (webase + (jlb >> 3) * 128) >> 1;
            #pragma unroll
            for (int p = 0; p < 4; ++p)
                wdst[wordbase + p] = f2b_pk(wv[2 * p], wv[2 * p + 1]);
        }
        __syncthreads();   // single barrier per K-step (double-buffered s_w)
        const ushort* swb = s_w[r & 1];
        bf16x8 a0 = *(const bf16x8*)(&swb[((w * 2 + 0) * 4 + quad) * 128 + l16 * 8]);
        bf16x8 a1 = *(const bf16x8*)(&swb[((w * 2 + 1) * 4 + quad) * 128 + l16 * 8]);
        asum[0] = __builtin_amdgcn_mfma_f32_16x16x32_bf16(a0, ones, asum[0], 0, 0, 0);
        asum[1] = __builtin_amdgcn_mfma_f32_16x16x32_bf16(a1, ones, asum[1], 0, 0, 0);
        #pragma unroll
        for (int dt = 0; dt < 8; ++dt) {
            bf16x8 bf = *(const bf16x8*)(hTb + (((size_t)(dt * 16 + l16)) << 10) + j0 + quad * 8);
            acc[0][dt] = __builtin_amdgcn_mfma_f32_16x16x32_bf16(a0, bf, acc[0][dt], 0, 0, 0);
            acc[1][dt] = __builtin_amdgcn_mfma_f32_16x16x32_bf16(a1, bf, acc[1][dt], 0, 0, 0);
        }
    }

    // row sums (all cols of asum are equal; lanes with l16==0 publish)
    if (l16 == 0) {
        #pragma unroll
        for (int it = 0; it < 2; ++it)
            #pragma unroll
            for (int rr = 0; rr < 4; ++rr)
                s_sum[w][it * 16 + quad * 4 + rr] = asum[it][rr];
    }
    __syncthreads();

    #pragma unroll
    for (int half = 0; half < 2; ++half) {
        float rsv[4];
        #pragma unroll
        for (int rr = 0; rr < 4; ++rr) rsv[rr] = 1.f / s_sum[w][half * 16 + quad * 4 + rr];
        #pragma unroll
        for (int dt = 0; dt < 8; ++dt)
            #pragma unroll
            for (int rr = 0; rr < 4; ++rr)
                s_ep[(quad * 4 + rr) * 520 + w * 128 + dt * 16 + l16] = acc[half][dt][rr] * rsv[rr];
        __syncthreads();
        #pragma unroll
        for (int q = 0; q < 4; ++q) {
            int ir = w * 4 + q;
            int ig = i0 + half * 16 + ir;
            float4 p0 = *(const float4*)(&s_ep[ir * 520 + lane * 8]);
            float4 p1 = *(const float4*)(&s_ep[ir * 520 + lane * 8 + 4]);
            const float* xp = X + (((size_t)((b << 10) + ig)) << 9) + lane * 8;
            float4 x0 = *(const float4*)(xp);
            float4 x1 = *(const float4*)(xp + 4);
            float v[8] = {p0.x + x0.x, p0.y + x0.y, p0.z + x0.z, p0.w + x0.w,
                          p1.x + x1.x, p1.y + x1.y, p1.z + x1.z, p1.w + x1.w};
            float s1 = 0.f, s2 = 0.f;
            #pragma unroll
            for (int u = 0; u < 8; ++u) { s1 += v[u]; s2 += v[u] * v[u]; }
            #pragma unroll
            for (int off = 1; off < 64; off <<= 1) { s1 += __shfl_xor(s1, off); s2 += __shfl_xor(s2, off); }
            float mean = s1 * (1.f / 512.f);
            float var  = s2 * (1.f / 512.f) - mean * mean;
            float rstd = rsqrtf(var + 1e-5f);
            int f0i = lane * 8;
            float4 g0 = *(const float4*)(gamma + f0i);
            float4 g1 = *(const float4*)(gamma + f0i + 4);
            float4 be0 = *(const float4*)(beta + f0i);
            float4 be1 = *(const float4*)(beta + f0i + 4);
            float* op = out + (((size_t)((b << 10) + ig)) << 9) + f0i;
            float4 o0, o1;
            o0.x = (v[0] - mean) * rstd * g0.x + be0.x;
            o0.y = (v[1] - mean) * rstd * g0.y + be0.y;
            o0.z = (v[2] - mean) * rstd * g0.z + be0.z;
            o0.w = (v[3] - mean) * rstd * g0.w + be0.w;
            o1.x = (v[4] - mean) * rstd * g1.x + be1.x;
            o1.y = (v[5] - mean) * rstd * g1.y + be1.y;
            o1.z = (v[6] - mean) * rstd * g1.z + be1.z;
            o1.w = (v[7] - mean) * rstd * g1.w + be1.w;
            *(float4*)op = o0;
            *(float4*)(op + 4) = o1;
        }
        __syncthreads();
    }
}

extern "C" void kernel_launch(void* const* d_in, const int* in_sizes, int n_in,
                              void* d_out, int out_size, void* d_ws, size_t ws_size,
                              hipStream_t stream) {
    const float* x     = (const float*)d_in[0];
    const int*   mask  = (const int*)d_in[1];
    const float* W     = (const float*)d_in[2];
    const float* a_src = (const float*)d_in[3];
    const float* a_dst = (const float*)d_in[4];
    const float* gamma = (const float*)d_in[5];
    const float* beta  = (const float*)d_in[6];
    float* out = (float*)d_out;

    ushort* hT = (ushort*)d_ws;                            // 8*512*1024 bf16 = 8 MB
    float* ei = (float*)((char*)d_ws + 8388608);           // 8*4*1024 f32
    float* ej = ei + 32768;

    gemm_xw<<<dim3(4, 64), 256, 0, stream>>>(x, W, hT);
    eij_kernel<<<dim3(32, 8), 256, 0, stream>>>(hT, a_src, a_dst, ei, ej);
    attn_pv<<<dim3(32, 8), 256, 0, stream>>>(hT, ei, ej, mask, x, gamma, beta, out);
}

// Round 3
// 177.402 us; speedup vs baseline: 1.8873x; 1.0117x over previous
//
#include <hip/hip_runtime.h>
#include <math.h>

#define Bsz 8
#define Nn 1024
#define Ff 512
#define Hh 4
#define Dd 128

typedef float f32x4 __attribute__((ext_vector_type(4)));
typedef short bf16x8 __attribute__((ext_vector_type(8)));

__device__ inline uint f2b1(float a) {
    union { float f; uint u; } v; v.f = a;
    return (v.u + 0x7fffu + ((v.u >> 16) & 1u)) >> 16;   // RNE f32->bf16
}
__device__ inline uint f2b_pk(float a, float b) { return f2b1(a) | (f2b1(b) << 16); }

// ============ Kernel 1: hT = (x@W)^T in bf16, + fused e_i/e_j partials ============
// Block 256 = 4 waves. Tile 128(m) x 64(n). Wave w: rows w*32..w*32+31, all 64 n.
// Grid (8 n-blocks, 64 m-blocks) = 512 blocks -> 2 blocks/CU.
__global__ __launch_bounds__(256, 4) void gemm_xw(const float* __restrict__ X,
                                                  const float* __restrict__ Wm,
                                                  const float* __restrict__ a_src,
                                                  const float* __restrict__ a_dst,
                                                  ushort* __restrict__ hT,
                                                  float* __restrict__ ei,
                                                  float* __restrict__ ej) {
    __shared__ ushort Asl[4096];   // 128m x 32k frag-major
    __shared__ ushort Bsl[2048];   // 64n x 32k frag-major
    const int tid = threadIdx.x;
    const int bm = blockIdx.y * 128;
    const int bn = blockIdx.x * 64;
    const int w = tid >> 6, lane = tid & 63, quad = lane >> 4, l16 = lane & 15;

    f32x4 z = {0.f, 0.f, 0.f, 0.f};
    f32x4 acc[2][4];
    #pragma unroll
    for (int i = 0; i < 2; ++i)
        #pragma unroll
        for (int j = 0; j < 4; ++j) acc[i][j] = z;

    const int am = tid >> 1, akh = (tid & 1) * 16;       // A: row am, k-half akh
    const int bkp = (tid >> 3) & 15, bnc = (tid & 7) * 8; // B: k-pair, n-chunk (tid<128)

    for (int k0 = 0; k0 < Ff; k0 += 32) {
        // stage A (128 x 32 fp32 -> bf16 frag-major)
        const float4* xp = (const float4*)(X + (size_t)(bm + am) * Ff + k0 + akh);
        float4 f0 = xp[0], f1 = xp[1], f2 = xp[2], f3 = xp[3];
        int kb = akh >> 3;
        uint4 w0 = { f2b_pk(f0.x, f0.y), f2b_pk(f0.z, f0.w), f2b_pk(f1.x, f1.y), f2b_pk(f1.z, f1.w) };
        uint4 w1 = { f2b_pk(f2.x, f2.y), f2b_pk(f2.z, f2.w), f2b_pk(f3.x, f3.y), f2b_pk(f3.z, f3.w) };
        *(uint4*)(&Asl[((am >> 4) * 4 + kb) * 128 + (am & 15) * 8]) = w0;
        *(uint4*)(&Asl[((am >> 4) * 4 + kb + 1) * 128 + (am & 15) * 8]) = w1;
        // stage B (32 x 64 fp32 -> bf16 frag-major) — threads 0..127
        if (tid < 128) {
            const float* wp = Wm + (size_t)(k0 + bkp * 2) * Ff + bn + bnc;
            float4 r0a = *(const float4*)(wp),      r0b = *(const float4*)(wp + 4);
            float4 r1a = *(const float4*)(wp + Ff), r1b = *(const float4*)(wp + Ff + 4);
            float r0[8] = {r0a.x, r0a.y, r0a.z, r0a.w, r0b.x, r0b.y, r0b.z, r0b.w};
            float r1[8] = {r1a.x, r1a.y, r1a.z, r1a.w, r1b.x, r1b.y, r1b.z, r1b.w};
            #pragma unroll
            for (int n = 0; n < 8; ++n) {
                int nl = bnc + n;
                int el = ((nl >> 4) * 4 + (bkp >> 2)) * 128 + (nl & 15) * 8 + (bkp & 3) * 2;
                ((uint*)Bsl)[el >> 1] = f2b_pk(r0[n], r1[n]);
            }
        }
        __syncthreads();
        bf16x8 a[2], bb[4];
        #pragma unroll
        for (int mt = 0; mt < 2; ++mt)
            a[mt] = *(const bf16x8*)(&Asl[((w * 2 + mt) * 4 + quad) * 128 + l16 * 8]);
        #pragma unroll
        for (int nt = 0; nt < 4; ++nt)
            bb[nt] = *(const bf16x8*)(&Bsl[(nt * 4 + quad) * 128 + l16 * 8]);
        #pragma unroll
        for (int mt = 0; mt < 2; ++mt)
            #pragma unroll
            for (int nt = 0; nt < 4; ++nt)
                acc[mt][nt] = __builtin_amdgcn_mfma_f32_16x16x32_bf16(a[mt], bb[nt], acc[mt][nt], 0, 0, 0);
        __syncthreads();
    }

    // epilogue 1: hT write (bf16), 4 consecutive m packed per uint2
    #pragma unroll
    for (int mt = 0; mt < 2; ++mt) {
        int mrow = bm + w * 32 + mt * 16 + quad * 4;
        int bb_ = mrow >> 10, nseq = mrow & 1023;
        #pragma unroll
        for (int nt = 0; nt < 4; ++nt) {
            int hd = bn + nt * 16 + l16;
            uint2 pv;
            pv.x = f2b_pk(acc[mt][nt][0], acc[mt][nt][1]);
            pv.y = f2b_pk(acc[mt][nt][2], acc[mt][nt][3]);
            *(uint2*)(hT + (((size_t)(bb_ * 512 + hd)) << 10) + nseq) = pv;
        }
    }

    // epilogue 2: e_i/e_j partials (this block covers hd = bn..bn+63, one head h = bn>>7)
    {
        float as4[4], ad4[4];
        #pragma unroll
        for (int nt = 0; nt < 4; ++nt) {
            as4[nt] = a_src[bn + nt * 16 + l16];
            ad4[nt] = a_dst[bn + nt * 16 + l16];
        }
        const int h = bn >> 7;
        #pragma unroll
        for (int mt = 0; mt < 2; ++mt) {
            #pragma unroll
            for (int rr = 0; rr < 4; ++rr) {
                float v1 = 0.f, v2 = 0.f;
                #pragma unroll
                for (int nt = 0; nt < 4; ++nt) {
                    v1 += acc[mt][nt][rr] * as4[nt];
                    v2 += acc[mt][nt][rr] * ad4[nt];
                }
                #pragma unroll
                for (int off = 1; off < 16; off <<= 1) {
                    v1 += __shfl_xor(v1, off);
                    v2 += __shfl_xor(v2, off);
                }
                if (l16 == 0) {
                    int m = bm + w * 32 + mt * 16 + quad * 4 + rr;
                    int bb_ = m >> 10, n = m & 1023;
                    atomicAdd(ei + ((bb_ * 4 + h) << 10) + n, v1);
                    atomicAdd(ej + ((bb_ * 4 + h) << 10) + n, v2);
                }
            }
        }
    }
}

// ============ Kernel 2: barrier-free attention + PV MFMA + residual + LayerNorm ============
// Block 256 = 4 waves, wave w = head w. 16 i-rows/block. Grid (64, 8) = 512 blocks.
__global__ __launch_bounds__(256, 4) void attn_pv(const ushort* __restrict__ hT,
                                                  const float* __restrict__ ei_g,
                                                  const float* __restrict__ ej_g,
                                                  const int* __restrict__ mask,
                                                  const float* __restrict__ X,
                                                  const float* __restrict__ gamma,
                                                  const float* __restrict__ beta,
                                                  float* __restrict__ out) {
    __shared__ float s_ep[16 * 516];   // 33 KB epilogue transpose tile, stride 516 (2-way only)

    const int b = blockIdx.y, i0 = blockIdx.x * 16;
    const int tid = threadIdx.x;
    const int w = tid >> 6, lane = tid & 63, quad = lane >> 4, l16 = lane & 15;

    const float* ejh = ej_g + ((b * 4 + w) << 10);
    const int* mkb = mask + (b << 10);

    // per-head max_j e_j (upper bound for exact softmax shift; leaky is monotone)
    float maxej = -3.0e38f;
    #pragma unroll
    for (int k = 0; k < 16; ++k) maxej = fmaxf(maxej, ejh[lane + 64 * k]);
    #pragma unroll
    for (int off = 1; off < 64; off <<= 1) maxej = fmaxf(maxej, __shfl_xor(maxej, off));

    // this lane's A-row: i = i0 + l16
    const float ei_r = ei_g[((b * 4 + w) << 10) + i0 + l16];
    const int mi_r = mkb[i0 + l16];
    float m_r;
    { float t = ei_r + maxej; m_r = mi_r ? fmaxf(t, 0.2f * t) : -1e9f; }

    f32x4 z = {0.f, 0.f, 0.f, 0.f};
    f32x4 acc[8], asum = z;
    #pragma unroll
    for (int dt = 0; dt < 8; ++dt) acc[dt] = z;
    bf16x8 ones;
    #pragma unroll
    for (int q = 0; q < 8; ++q) ones[q] = (short)0x3F80;   // bf16 1.0

    const ushort* hTb = hT + (((size_t)(b * 512 + w * 128)) << 10);

    for (int r = 0; r < 32; ++r) {
        const int jq = r * 32 + quad * 8;      // this lane's 8 k-elements (j-neighbors)
        float4 e0 = *(const float4*)(ejh + jq);
        float4 e1 = *(const float4*)(ejh + jq + 4);
        int4 q0 = *(const int4*)(mkb + jq);
        int4 q1 = *(const int4*)(mkb + jq + 4);
        float ev[8] = {e0.x, e0.y, e0.z, e0.w, e1.x, e1.y, e1.z, e1.w};
        int   mv[8] = {q0.x, q0.y, q0.z, q0.w, q1.x, q1.y, q1.z, q1.w};
        float wv[8];
        #pragma unroll
        for (int u = 0; u < 8; ++u) {
            float t = ei_r + ev[u];
            float l = fmaxf(t, 0.2f * t);               // leaky_relu 0.2
            float lg = (mi_r && mv[u]) ? l : -1e9f;
            wv[u] = __expf(lg - m_r);                   // un-normalized weight
        }
        union { uint4 u; bf16x8 v; } af;
        af.u.x = f2b_pk(wv[0], wv[1]);
        af.u.y = f2b_pk(wv[2], wv[3]);
        af.u.z = f2b_pk(wv[4], wv[5]);
        af.u.w = f2b_pk(wv[6], wv[7]);
        asum = __builtin_amdgcn_mfma_f32_16x16x32_bf16(af.v, ones, asum, 0, 0, 0);
        #pragma unroll
        for (int dt = 0; dt < 8; ++dt) {
            bf16x8 bf = *(const bf16x8*)(hTb + (((size_t)(dt * 16 + l16)) << 10) + jq);
            acc[dt] = __builtin_amdgcn_mfma_f32_16x16x32_bf16(af.v, bf, acc[dt], 0, 0, 0);
        }
    }

    // normalize (lane already holds its rows' sums: D cols are identical) + transpose via LDS
    float rsv[4];
    #pragma unroll
    for (int rr = 0; rr < 4; ++rr) rsv[rr] = 1.f / asum[rr];
    #pragma unroll
    for (int dt = 0; dt < 8; ++dt)
        #pragma unroll
        for (int rr = 0; rr < 4; ++rr)
            s_ep[(quad * 4 + rr) * 516 + w * 128 + dt * 16 + l16] = acc[dt][rr] * rsv[rr];
    __syncthreads();

    // residual + LayerNorm: wave w owns rows w*4..w*4+3
    #pragma unroll
    for (int q = 0; q < 4; ++q) {
        int ir = w * 4 + q;
        int ig = i0 + ir;
        float4 p0 = *(const float4*)(&s_ep[ir * 516 + lane * 8]);
        float4 p1 = *(const float4*)(&s_ep[ir * 516 + lane * 8 + 4]);
        const float* xp = X + (((size_t)((b << 10) + ig)) << 9) + lane * 8;
        float4 x0 = *(const float4*)(xp);
        float4 x1 = *(const float4*)(xp + 4);
        float v[8] = {p0.x + x0.x, p0.y + x0.y, p0.z + x0.z, p0.w + x0.w,
                      p1.x + x1.x, p1.y + x1.y, p1.z + x1.z, p1.w + x1.w};
        float s1 = 0.f, s2 = 0.f;
        #pragma unroll
        for (int u = 0; u < 8; ++u) { s1 += v[u]; s2 += v[u] * v[u]; }
        #pragma unroll
        for (int off = 1; off < 64; off <<= 1) { s1 += __shfl_xor(s1, off); s2 += __shfl_xor(s2, off); }
        float mean = s1 * (1.f / 512.f);
        float var  = s2 * (1.f / 512.f) - mean * mean;
        float rstd = rsqrtf(var + 1e-5f);
        int f0i = lane * 8;
        float4 g0 = *(const float4*)(gamma + f0i);
        float4 g1 = *(const float4*)(gamma + f0i + 4);
        float4 be0 = *(const float4*)(beta + f0i);
        float4 be1 = *(const float4*)(beta + f0i + 4);
        float* op = out + (((size_t)((b << 10) + ig)) << 9) + f0i;
        float4 o0, o1;
        o0.x = (v[0] - mean) * rstd * g0.x + be0.x;
        o0.y = (v[1] - mean) * rstd * g0.y + be0.y;
        o0.z = (v[2] - mean) * rstd * g0.z + be0.z;
        o0.w = (v[3] - mean) * rstd * g0.w + be0.w;
        o1.x = (v[4] - mean) * rstd * g1.x + be1.x;
        o1.y = (v[5] - mean) * rstd * g1.y + be1.y;
        o1.z = (v[6] - mean) * rstd * g1.z + be1.z;
        o1.w = (v[7] - mean) * rstd * g1.w + be1.w;
        *(float4*)op = o0;
        *(float4*)(op + 4) = o1;
    }
}

extern "C" void kernel_launch(void* const* d_in, const int* in_sizes, int n_in,
                              void* d_out, int out_size, void* d_ws, size_t ws_size,
                              hipStream_t stream) {
    const float* x     = (const float*)d_in[0];
    const int*   mask  = (const int*)d_in[1];
    const float* W     = (const float*)d_in[2];
    const float* a_src = (const float*)d_in[3];
    const float* a_dst = (const float*)d_in[4];
    const float* gamma = (const float*)d_in[5];
    const float* beta  = (const float*)d_in[6];
    float* out = (float*)d_out;

    ushort* hT = (ushort*)d_ws;                            // 8*512*1024 bf16 = 8 MB
    float* ei = (float*)((char*)d_ws + 8388608);           // 8*4*1024 f32
    float* ej = ei + 32768;

    hipMemsetAsync(ei, 0, 2 * 32768 * sizeof(float), stream);
    gemm_xw<<<dim3(8, 64), 256, 0, stream>>>(x, W, a_src, a_dst, hT, ei, ej);
    attn_pv<<<dim3(64, 8), 256, 0, stream>>>(hT, ei, ej, mask, x, gamma, beta, out);
}

// Round 4
// 176.572 us; speedup vs baseline: 1.8962x; 1.0047x over previous
//
#include <hip/hip_runtime.h>
#include <math.h>

#define Bsz 8
#define Nn 1024
#define Ff 512
#define Hh 4
#define Dd 128

typedef float f32x4 __attribute__((ext_vector_type(4)));
typedef short bf16x8 __attribute__((ext_vector_type(8)));

__device__ inline uint f2b1(float a) {
    union { float f; uint u; } v; v.f = a;
    return (v.u + 0x7fffu + ((v.u >> 16) & 1u)) >> 16;   // RNE f32->bf16
}
__device__ inline uint f2b_pk(float a, float b) { return f2b1(a) | (f2b1(b) << 16); }

// ============ Kernel 0: pre-swizzle X and W into fragment-major bf16 ============
// Xc chunk layout: flat = ((mtile*64 + kblk)*16 + m15)*8 + k7  (mtile = row/16, kblk = k/8)
// Wc chunk layout: flat = ((ntile*64 + kblk)*16 + n15)*8 + k7  (value = W[k][n])
__global__ __launch_bounds__(256) void conv_xw(const float* __restrict__ X,
                                               const float* __restrict__ Wm,
                                               ushort* __restrict__ Xc,
                                               ushort* __restrict__ Wc) {
    const int bi = blockIdx.x, tid = threadIdx.x;
    if (bi < 512) {
        // X: block = mtile, thread: kblk = tid>>2, rows (tid&3)*4 .. +3
        const int mtile = bi, kblk = tid >> 2, m15b = (tid & 3) * 4;
        #pragma unroll
        for (int c = 0; c < 4; ++c) {
            int m15 = m15b + c;
            const float4* xp = (const float4*)(X + (size_t)(mtile * 16 + m15) * Ff + kblk * 8);
            float4 f0 = xp[0], f1 = xp[1];
            uint4 o = { f2b_pk(f0.x, f0.y), f2b_pk(f0.z, f0.w),
                        f2b_pk(f1.x, f1.y), f2b_pk(f1.z, f1.w) };
            *(uint4*)(Xc + (((size_t)(mtile * 64 + kblk) * 16 + m15) << 3)) = o;
        }
    } else {
        // W: chunk id = (ntile,kblk,n15); 32768 chunks over 128 blocks
        int id = (bi - 512) * 256 + tid;
        int ntile = id >> 10, kblk = (id >> 4) & 63, n15 = id & 15;
        float v[8];
        #pragma unroll
        for (int u = 0; u < 8; ++u)
            v[u] = Wm[(size_t)(kblk * 8 + u) * Ff + ntile * 16 + n15];
        uint4 o = { f2b_pk(v[0], v[1]), f2b_pk(v[2], v[3]),
                    f2b_pk(v[4], v[5]), f2b_pk(v[6], v[7]) };
        *(uint4*)(Wc + ((size_t)id << 3)) = o;
    }
}

// ============ Kernel 1: barrier-free zero-LDS GEMM hT = (x@W)^T + exact e_i/e_j ============
// 1-D grid 512, XCD swizzle: b = idx&7. Block = 64m x 128n (one head). Wave = 16m x 128n.
__global__ __launch_bounds__(256, 4) void gemm_xw(const ushort* __restrict__ Xc,
                                                  const ushort* __restrict__ Wc,
                                                  const float* __restrict__ a_src,
                                                  const float* __restrict__ a_dst,
                                                  ushort* __restrict__ hT,
                                                  float* __restrict__ ei,
                                                  float* __restrict__ ej) {
    const int idx = blockIdx.x;
    const int b = idx & 7, sub = idx >> 3;
    const int mi = sub & 15, nc = sub >> 4;          // mi: 64-row group in b; nc: head
    const int tid = threadIdx.x;
    const int w = tid >> 6, lane = tid & 63, quad = lane >> 4, l16 = lane & 15;
    const int mtile = (b * 16 + mi) * 4 + w;         // global 16-row tile

    f32x4 z = {0.f, 0.f, 0.f, 0.f};
    f32x4 acc[8];
    #pragma unroll
    for (int nt = 0; nt < 8; ++nt) acc[nt] = z;

    const ushort* ap = Xc + ((size_t)mtile << 13) + quad * 128 + l16 * 8;
    const ushort* bp = Wc + ((size_t)nc << 16) + quad * 128 + l16 * 8;

    #pragma unroll 2
    for (int s = 0; s < 16; ++s) {
        bf16x8 a = *(const bf16x8*)(ap + s * 512);
        bf16x8 bb[8];
        #pragma unroll
        for (int nt = 0; nt < 8; ++nt)
            bb[nt] = *(const bf16x8*)(bp + nt * 8192 + s * 512);
        #pragma unroll
        for (int nt = 0; nt < 8; ++nt)
            acc[nt] = __builtin_amdgcn_mfma_f32_16x16x32_bf16(a, bb[nt], acc[nt], 0, 0, 0);
    }

    // epilogue 1: hT[b*512+hd][nseq] bf16; rows m = quad*4+rr, cols hd = nc*128+nt*16+l16
    const int nseq = (mi * 4 + w) * 16 + quad * 4;   // 4 consecutive rows rr=0..3
    #pragma unroll
    for (int nt = 0; nt < 8; ++nt) {
        uint2 pv;
        pv.x = f2b_pk(acc[nt][0], acc[nt][1]);
        pv.y = f2b_pk(acc[nt][2], acc[nt][3]);
        *(uint2*)(hT + (((size_t)(b * 512 + nc * 128 + nt * 16 + l16)) << 10) + nseq) = pv;
    }

    // epilogue 2: exact e_i/e_j for this wave's 16 rows (head nc), no atomics
    {
        float as4[8], ad4[8];
        #pragma unroll
        for (int nt = 0; nt < 8; ++nt) {
            as4[nt] = a_src[nc * 128 + nt * 16 + l16];
            ad4[nt] = a_dst[nc * 128 + nt * 16 + l16];
        }
        #pragma unroll
        for (int rr = 0; rr < 4; ++rr) {
            float v1 = 0.f, v2 = 0.f;
            #pragma unroll
            for (int nt = 0; nt < 8; ++nt) {
                v1 += acc[nt][rr] * as4[nt];
                v2 += acc[nt][rr] * ad4[nt];
            }
            #pragma unroll
            for (int off = 1; off < 16; off <<= 1) {
                v1 += __shfl_xor(v1, off);
                v2 += __shfl_xor(v2, off);
            }
            if (l16 == 0) {
                int n = nseq + rr;
                ei[((b * 4 + nc) << 10) + n] = v1;
                ej[((b * 4 + nc) << 10) + n] = v2;
            }
        }
    }
}

// ============ Kernel 2: barrier-free attention + PV MFMA + residual + LayerNorm ============
// 1-D grid 512, XCD swizzle: b = idx&7, i0 = (idx>>3)*16. Wave w = head w.
__global__ __launch_bounds__(256, 4) void attn_pv(const ushort* __restrict__ hT,
                                                  const float* __restrict__ ei_g,
                                                  const float* __restrict__ ej_g,
                                                  const int* __restrict__ mask,
                                                  const float* __restrict__ X,
                                                  const float* __restrict__ gamma,
                                                  const float* __restrict__ beta,
                                                  float* __restrict__ out) {
    __shared__ float s_ep[16 * 516];   // 33 KB epilogue transpose tile, stride 516

    const int idx = blockIdx.x;
    const int b = idx & 7, i0 = (idx >> 3) * 16;
    const int tid = threadIdx.x;
    const int w = tid >> 6, lane = tid & 63, quad = lane >> 4, l16 = lane & 15;

    const float* ejh = ej_g + ((b * 4 + w) << 10);
    const int* mkb = mask + (b << 10);

    // per-head max_j e_j (upper bound for exact softmax shift; leaky is monotone)
    float maxej = -3.0e38f;
    #pragma unroll
    for (int k = 0; k < 16; ++k) maxej = fmaxf(maxej, ejh[lane + 64 * k]);
    #pragma unroll
    for (int off = 1; off < 64; off <<= 1) maxej = fmaxf(maxej, __shfl_xor(maxej, off));

    // this lane's A-row: i = i0 + l16
    const float ei_r = ei_g[((b * 4 + w) << 10) + i0 + l16];
    const int mi_r = mkb[i0 + l16];
    float m_r;
    { float t = ei_r + maxej; m_r = mi_r ? fmaxf(t, 0.2f * t) : -1e9f; }

    f32x4 z = {0.f, 0.f, 0.f, 0.f};
    f32x4 acc[8], asum = z;
    #pragma unroll
    for (int dt = 0; dt < 8; ++dt) acc[dt] = z;
    bf16x8 ones;
    #pragma unroll
    for (int q = 0; q < 8; ++q) ones[q] = (short)0x3F80;   // bf16 1.0

    const ushort* hTb = hT + (((size_t)(b * 512 + w * 128)) << 10);

    for (int r = 0; r < 32; ++r) {
        const int jq = r * 32 + quad * 8;      // this lane's 8 k-elements (j-neighbors)
        float4 e0 = *(const float4*)(ejh + jq);
        float4 e1 = *(const float4*)(ejh + jq + 4);
        int4 q0 = *(const int4*)(mkb + jq);
        int4 q1 = *(const int4*)(mkb + jq + 4);
        float ev[8] = {e0.x, e0.y, e0.z, e0.w, e1.x, e1.y, e1.z, e1.w};
        int   mv[8] = {q0.x, q0.y, q0.z, q0.w, q1.x, q1.y, q1.z, q1.w};
        float wv[8];
        #pragma unroll
        for (int u = 0; u < 8; ++u) {
            float t = ei_r + ev[u];
            float l = fmaxf(t, 0.2f * t);               // leaky_relu 0.2
            float lg = (mi_r && mv[u]) ? l : -1e9f;
            wv[u] = __expf(lg - m_r);                   // un-normalized weight
        }
        union { uint4 u; bf16x8 v; } af;
        af.u.x = f2b_pk(wv[0], wv[1]);
        af.u.y = f2b_pk(wv[2], wv[3]);
        af.u.z = f2b_pk(wv[4], wv[5]);
        af.u.w = f2b_pk(wv[6], wv[7]);
        asum = __builtin_amdgcn_mfma_f32_16x16x32_bf16(af.v, ones, asum, 0, 0, 0);
        #pragma unroll
        for (int dt = 0; dt < 8; ++dt) {
            bf16x8 bf = *(const bf16x8*)(hTb + (((size_t)(dt * 16 + l16)) << 10) + jq);
            acc[dt] = __builtin_amdgcn_mfma_f32_16x16x32_bf16(af.v, bf, acc[dt], 0, 0, 0);
        }
    }

    // normalize (lane holds its rows' sums: D cols identical) + transpose via LDS
    float rsv[4];
    #pragma unroll
    for (int rr = 0; rr < 4; ++rr) rsv[rr] = 1.f / asum[rr];
    #pragma unroll
    for (int dt = 0; dt < 8; ++dt)
        #pragma unroll
        for (int rr = 0; rr < 4; ++rr)
            s_ep[(quad * 4 + rr) * 516 + w * 128 + dt * 16 + l16] = acc[dt][rr] * rsv[rr];
    __syncthreads();

    // residual + LayerNorm: wave w owns rows w*4..w*4+3
    #pragma unroll
    for (int q = 0; q < 4; ++q) {
        int ir = w * 4 + q;
        int ig = i0 + ir;
        float4 p0 = *(const float4*)(&s_ep[ir * 516 + lane * 8]);
        float4 p1 = *(const float4*)(&s_ep[ir * 516 + lane * 8 + 4]);
        const float* xp = X + (((size_t)((b << 10) + ig)) << 9) + lane * 8;
        float4 x0 = *(const float4*)(xp);
        float4 x1 = *(const float4*)(xp + 4);
        float v[8] = {p0.x + x0.x, p0.y + x0.y, p0.z + x0.z, p0.w + x0.w,
                      p1.x + x1.x, p1.y + x1.y, p1.z + x1.z, p1.w + x1.w};
        float s1 = 0.f, s2 = 0.f;
        #pragma unroll
        for (int u = 0; u < 8; ++u) { s1 += v[u]; s2 += v[u] * v[u]; }
        #pragma unroll
        for (int off = 1; off < 64; off <<= 1) { s1 += __shfl_xor(s1, off); s2 += __shfl_xor(s2, off); }
        float mean = s1 * (1.f / 512.f);
        float var  = s2 * (1.f / 512.f) - mean * mean;
        float rstd = rsqrtf(var + 1e-5f);
        int f0i = lane * 8;
        float4 g0 = *(const float4*)(gamma + f0i);
        float4 g1 = *(const float4*)(gamma + f0i + 4);
        float4 be0 = *(const float4*)(beta + f0i);
        float4 be1 = *(const float4*)(beta + f0i + 4);
        float* op = out + (((size_t)((b << 10) + ig)) << 9) + f0i;
        float4 o0, o1;
        o0.x = (v[0] - mean) * rstd * g0.x + be0.x;
        o0.y = (v[1] - mean) * rstd * g0.y + be0.y;
        o0.z = (v[2] - mean) * rstd * g0.z + be0.z;
        o0.w = (v[3] - mean) * rstd * g0.w + be0.w;
        o1.x = (v[4] - mean) * rstd * g1.x + be1.x;
        o1.y = (v[5] - mean) * rstd * g1.y + be1.y;
        o1.z = (v[6] - mean) * rstd * g1.z + be1.z;
        o1.w = (v[7] - mean) * rstd * g1.w + be1.w;
        *(float4*)op = o0;
        *(float4*)(op + 4) = o1;
    }
}

extern "C" void kernel_launch(void* const* d_in, const int* in_sizes, int n_in,
                              void* d_out, int out_size, void* d_ws, size_t ws_size,
                              hipStream_t stream) {
    const float* x     = (const float*)d_in[0];
    const int*   mask  = (const int*)d_in[1];
    const float* W     = (const float*)d_in[2];
    const float* a_src = (const float*)d_in[3];
    const float* a_dst = (const float*)d_in[4];
    const float* gamma = (const float*)d_in[5];
    const float* beta  = (const float*)d_in[6];
    float* out = (float*)d_out;

    ushort* hT = (ushort*)d_ws;                            // 8 MB
    ushort* Xc = hT + (size_t)8 * 512 * 1024;              // 8 MB bf16 swizzled X
    ushort* Wc = Xc + (size_t)8 * 1024 * 512;              // 0.5 MB bf16 swizzled W
    float* ei = (float*)(Wc + (size_t)512 * 512);          // 128 KB
    float* ej = ei + 32768;

    conv_xw<<<dim3(640), 256, 0, stream>>>(x, W, Xc, Wc);
    gemm_xw<<<dim3(512), 256, 0, stream>>>(Xc, Wc, a_src, a_dst, hT, ei, ej);
    attn_pv<<<dim3(512), 256, 0, stream>>>(hT, ei, ej, mask, x, gamma, beta, out);
}

// Round 6
// 171.402 us; speedup vs baseline: 1.9534x; 1.0302x over previous
//
#include <hip/hip_runtime.h>
#include <math.h>

#define Bsz 8
#define Nn 1024
#define Ff 512
#define Hh 4
#define Dd 128

typedef float f32x4 __attribute__((ext_vector_type(4)));
typedef short bf16x8 __attribute__((ext_vector_type(8)));

__device__ inline uint f2b1(float a) {
    union { float f; uint u; } v; v.f = a;
    return (v.u + 0x7fffu + ((v.u >> 16) & 1u)) >> 16;   // RNE f32->bf16
}
__device__ inline uint f2b_pk(float a, float b) { return f2b1(a) | (f2b1(b) << 16); }

// hT2 layout: el = ((b*32 + (j>>5))*512 + hd)*32 + (j&31)
//   -> one K-step's 16-row x 8-dt B-fragment reads for a wave = 8 KB CONTIGUOUS
//      (all 16 L2 channels) instead of 2KB-strided (2 channels).
// Wc layout:  el = ((nc*64 + kblk)*8 + nt)*16*8 + n15*8 + k7
//   -> per-step 8 B-loads contiguous 8 KB.

// ============ Kernel 0: pre-swizzle X and W into fragment-major bf16 ============
__global__ __launch_bounds__(256) void conv_xw(const float* __restrict__ X,
                                               const float* __restrict__ Wm,
                                               ushort* __restrict__ Xc,
                                               ushort* __restrict__ Wc) {
    const int bi = blockIdx.x, tid = threadIdx.x;
    if (bi < 512) {
        const int mtile = bi, kblk = tid >> 2, m15b = (tid & 3) * 4;
        #pragma unroll
        for (int c = 0; c < 4; ++c) {
            int m15 = m15b + c;
            const float4* xp = (const float4*)(X + (size_t)(mtile * 16 + m15) * Ff + kblk * 8);
            float4 f0 = xp[0], f1 = xp[1];
            uint4 o = { f2b_pk(f0.x, f0.y), f2b_pk(f0.z, f0.w),
                        f2b_pk(f1.x, f1.y), f2b_pk(f1.z, f1.w) };
            *(uint4*)(Xc + (((size_t)(mtile * 64 + kblk) * 16 + m15) << 3)) = o;
        }
    } else {
        // id = ((nc*64 + kblk)*8 + nt)*16 + n15 ; value rows k = kblk*8+u, col = nc*128+nt*16+n15
        int id = (bi - 512) * 256 + tid;
        int n15 = id & 15, nt = (id >> 4) & 7, kblk = (id >> 7) & 63, nc = id >> 13;
        int col = nc * 128 + nt * 16 + n15;
        float v[8];
        #pragma unroll
        for (int u = 0; u < 8; ++u)
            v[u] = Wm[(size_t)(kblk * 8 + u) * Ff + col];
        uint4 o = { f2b_pk(v[0], v[1]), f2b_pk(v[2], v[3]),
                    f2b_pk(v[4], v[5]), f2b_pk(v[6], v[7]) };
        *(uint4*)(Wc + ((size_t)id << 3)) = o;
    }
}

// ============ Kernel 1: barrier-free zero-LDS GEMM hT2 = (x@W)^T + exact e_i/e_j ============
__global__ __launch_bounds__(256, 4) void gemm_xw(const ushort* __restrict__ Xc,
                                                  const ushort* __restrict__ Wc,
                                                  const float* __restrict__ a_src,
                                                  const float* __restrict__ a_dst,
                                                  ushort* __restrict__ hT,
                                                  float* __restrict__ ei,
                                                  float* __restrict__ ej) {
    const int idx = blockIdx.x;
    const int b = idx & 7, sub = idx >> 3;
    const int mi = sub & 15, nc = sub >> 4;
    const int tid = threadIdx.x;
    const int w = tid >> 6, lane = tid & 63, quad = lane >> 4, l16 = lane & 15;
    const int mtile = (b * 16 + mi) * 4 + w;

    f32x4 z = {0.f, 0.f, 0.f, 0.f};
    f32x4 acc[8];
    #pragma unroll
    for (int nt = 0; nt < 8; ++nt) acc[nt] = z;

    const ushort* ap = Xc + ((size_t)mtile << 13) + quad * 128 + l16 * 8;
    // Wc: el = (((nc*64 + kblk)*8 + nt)*16 + n15)*8 ; kblk = s*4+quad
    const ushort* bp = Wc + ((size_t)nc << 16) + quad * 1024 + l16 * 8;

    #pragma unroll 2
    for (int s = 0; s < 16; ++s) {
        bf16x8 a = *(const bf16x8*)(ap + s * 512);
        bf16x8 bb[8];
        #pragma unroll
        for (int nt = 0; nt < 8; ++nt)
            bb[nt] = *(const bf16x8*)(bp + s * 4096 + nt * 128);
        #pragma unroll
        for (int nt = 0; nt < 8; ++nt)
            acc[nt] = __builtin_amdgcn_mfma_f32_16x16x32_bf16(a, bb[nt], acc[nt], 0, 0, 0);
    }

    // epilogue 1: hT2 store; rows m(=j) = nseq+rr, cols hd = nc*128+nt*16+l16
    const int nseq = (mi * 4 + w) * 16 + quad * 4;   // multiple of 4, (nseq&31)+3 <= 31
    const int jb = nseq >> 5, js = nseq & 31;
    #pragma unroll
    for (int nt = 0; nt < 8; ++nt) {
        uint2 pv;
        pv.x = f2b_pk(acc[nt][0], acc[nt][1]);
        pv.y = f2b_pk(acc[nt][2], acc[nt][3]);
        int hd = nc * 128 + nt * 16 + l16;
        *(uint2*)(hT + ((size_t)(b * 32 + jb)) * 16384 + (size_t)hd * 32 + js) = pv;
    }

    // epilogue 2: exact e_i/e_j, no atomics
    {
        float as4[8], ad4[8];
        #pragma unroll
        for (int nt = 0; nt < 8; ++nt) {
            as4[nt] = a_src[nc * 128 + nt * 16 + l16];
            ad4[nt] = a_dst[nc * 128 + nt * 16 + l16];
        }
        #pragma unroll
        for (int rr = 0; rr < 4; ++rr) {
            float v1 = 0.f, v2 = 0.f;
            #pragma unroll
            for (int nt = 0; nt < 8; ++nt) {
                v1 += acc[nt][rr] * as4[nt];
                v2 += acc[nt][rr] * ad4[nt];
            }
            #pragma unroll
            for (int off = 1; off < 16; off <<= 1) {
                v1 += __shfl_xor(v1, off);
                v2 += __shfl_xor(v2, off);
            }
            if (l16 == 0) {
                int n = nseq + rr;
                ei[((b * 4 + nc) << 10) + n] = v1;
                ej[((b * 4 + nc) << 10) + n] = v2;
            }
        }
    }
}

// ============ Kernel 2: barrier-free attention + PV MFMA + residual + LayerNorm ============
// 256 thr = 4 waves, wave w = head w. 16 i-rows/block. 1-D grid 512, XCD swizzle b = idx&7.
__global__ __launch_bounds__(256, 4) void attn_pv(const ushort* __restrict__ hT,
                                                  const float* __restrict__ ei_g,
                                                  const float* __restrict__ ej_g,
                                                  const int* __restrict__ mask,
                                                  const float* __restrict__ X,
                                                  const float* __restrict__ gamma,
                                                  const float* __restrict__ beta,
                                                  float* __restrict__ out) {
    __shared__ float s_ep[16 * 516];   // 33 KB epilogue transpose tile

    const int idx = blockIdx.x;
    const int b = idx & 7, i0 = (idx >> 3) * 16;
    const int tid = threadIdx.x;
    const int w = tid >> 6, lane = tid & 63, quad = lane >> 4, l16 = lane & 15;

    const float* ejh = ej_g + ((b * 4 + w) << 10);
    const int* mkb = mask + (b << 10);

    // per-head max_j e_j (upper bound for exact softmax shift; leaky is monotone)
    float maxej = -3.0e38f;
    #pragma unroll
    for (int k = 0; k < 16; ++k) maxej = fmaxf(maxej, ejh[lane + 64 * k]);
    #pragma unroll
    for (int off = 1; off < 64; off <<= 1) maxej = fmaxf(maxej, __shfl_xor(maxej, off));

    const float ei_r = ei_g[((b * 4 + w) << 10) + i0 + l16];
    const int mi_r = mkb[i0 + l16];
    float m_r;
    { float t = ei_r + maxej; m_r = mi_r ? fmaxf(t, 0.2f * t) : -1e9f; }

    f32x4 z = {0.f, 0.f, 0.f, 0.f};
    f32x4 acc[8], asum = z;
    #pragma unroll
    for (int dt = 0; dt < 8; ++dt) acc[dt] = z;
    bf16x8 ones;
    #pragma unroll
    for (int q = 0; q < 8; ++q) ones[q] = (short)0x3F80;   // bf16 1.0

    // hT2 base for this (b, head w): per r-block advance 16384 el; within: (dt*16+l16)*32 + quad*8
    const ushort* hTb = hT + ((size_t)(b * 32)) * 16384 + (size_t)(w * 128) * 32 + l16 * 32 + quad * 8;

    for (int r = 0; r < 32; ++r) {
        const int jq = r * 32 + quad * 8;
        float4 e0 = *(const float4*)(ejh + jq);
        float4 e1 = *(const float4*)(ejh + jq + 4);
        int4 q0 = *(const int4*)(mkb + jq);
        int4 q1 = *(const int4*)(mkb + jq + 4);
        float ev[8] = {e0.x, e0.y, e0.z, e0.w, e1.x, e1.y, e1.z, e1.w};
        int   mv[8] = {q0.x, q0.y, q0.z, q0.w, q1.x, q1.y, q1.z, q1.w};
        float wv[8];
        #pragma unroll
        for (int u = 0; u < 8; ++u) {
            float t = ei_r + ev[u];
            float l = fmaxf(t, 0.2f * t);               // leaky_relu 0.2
            float lg = (mi_r && mv[u]) ? l : -1e9f;
            wv[u] = __expf(lg - m_r);                   // un-normalized weight
        }
        union { uint4 u; bf16x8 v; } af;
        af.u.x = f2b_pk(wv[0], wv[1]);
        af.u.y = f2b_pk(wv[2], wv[3]);
        af.u.z = f2b_pk(wv[4], wv[5]);
        af.u.w = f2b_pk(wv[6], wv[7]);
        asum = __builtin_amdgcn_mfma_f32_16x16x32_bf16(af.v, ones, asum, 0, 0, 0);
        const ushort* hr = hTb + (size_t)r * 16384;
        #pragma unroll
        for (int dt = 0; dt < 8; ++dt) {
            bf16x8 bf = *(const bf16x8*)(hr + dt * 512);
            acc[dt] = __builtin_amdgcn_mfma_f32_16x16x32_bf16(af.v, bf, acc[dt], 0, 0, 0);
        }
    }

    // normalize (lane holds its rows' sums: D cols identical) + transpose via LDS
    float rsv[4];
    #pragma unroll
    for (int rr = 0; rr < 4; ++rr) rsv[rr] = 1.f / asum[rr];
    #pragma unroll
    for (int dt = 0; dt < 8; ++dt)
        #pragma unroll
        for (int rr = 0; rr < 4; ++rr)
            s_ep[(quad * 4 + rr) * 516 + w * 128 + dt * 16 + l16] = acc[dt][rr] * rsv[rr];
    __syncthreads();

    // residual + LayerNorm: wave w owns rows w*4..w*4+3
    #pragma unroll
    for (int q = 0; q < 4; ++q) {
        int ir = w * 4 + q;
        int ig = i0 + ir;
        float4 p0 = *(const float4*)(&s_ep[ir * 516 + lane * 8]);
        float4 p1 = *(const float4*)(&s_ep[ir * 516 + lane * 8 + 4]);
        const float* xp = X + (((size_t)((b << 10) + ig)) << 9) + lane * 8;
        float4 x0 = *(const float4*)(xp);
        float4 x1 = *(const float4*)(xp + 4);
        float v[8] = {p0.x + x0.x, p0.y + x0.y, p0.z + x0.z, p0.w + x0.w,
                      p1.x + x1.x, p1.y + x1.y, p1.z + x1.z, p1.w + x1.w};
        float s1 = 0.f, s2 = 0.f;
        #pragma unroll
        for (int u = 0; u < 8; ++u) { s1 += v[u]; s2 += v[u] * v[u]; }
        #pragma unroll
        for (int off = 1; off < 64; off <<= 1) { s1 += __shfl_xor(s1, off); s2 += __shfl_xor(s2, off); }
        float mean = s1 * (1.f / 512.f);
        float var  = s2 * (1.f / 512.f) - mean * mean;
        float rstd = rsqrtf(var + 1e-5f);
        int f0i = lane * 8;
        float4 g0 = *(const float4*)(gamma + f0i);
        float4 g1 = *(const float4*)(gamma + f0i + 4);
        float4 be0 = *(const float4*)(beta + f0i);
        float4 be1 = *(const float4*)(beta + f0i + 4);
        float* op = out + (((size_t)((b << 10) + ig)) << 9) + f0i;
        float4 o0, o1;
        o0.x = (v[0] - mean) * rstd * g0.x + be0.x;
        o0.y = (v[1] - mean) * rstd * g0.y + be0.y;
        o0.z = (v[2] - mean) * rstd * g0.z + be0.z;
        o0.w = (v[3] - mean) * rstd * g0.w + be0.w;
        o1.x = (v[4] - mean) * rstd * g1.x + be1.x;
        o1.y = (v[5] - mean) * rstd * g1.y + be1.y;
        o1.z = (v[6] - mean) * rstd * g1.z + be1.z;
        o1.w = (v[7] - mean) * rstd * g1.w + be1.w;
        *(float4*)op = o0;
        *(float4*)(op + 4) = o1;
    }
}

extern "C" void kernel_launch(void* const* d_in, const int* in_sizes, int n_in,
                              void* d_out, int out_size, void* d_ws, size_t ws_size,
                              hipStream_t stream) {
    const float* x     = (const float*)d_in[0];
    const int*   mask  = (const int*)d_in[1];
    const float* W     = (const float*)d_in[2];
    const float* a_src = (const float*)d_in[3];
    const float* a_dst = (const float*)d_in[4];
    const float* gamma = (const float*)d_in[5];
    const float* beta  = (const float*)d_in[6];
    float* out = (float*)d_out;

    ushort* hT = (ushort*)d_ws;                            // 8 MB
    ushort* Xc = hT + (size_t)8 * 512 * 1024;              // 8 MB
    ushort* Wc = Xc + (size_t)8 * 1024 * 512;              // 0.5 MB
    float* ei = (float*)(Wc + (size_t)512 * 512);          // 128 KB
    float* ej = ei + 32768;

    conv_xw<<<dim3(640), 256, 0, stream>>>(x, W, Xc, Wc);
    gemm_xw<<<dim3(512), 256, 0, stream>>>(Xc, Wc, a_src, a_dst, hT, ei, ej);
    attn_pv<<<dim3(512), 256, 0, stream>>>(hT, ei, ej, mask, x, gamma, beta, out);
}

// Round 7
// 133.819 us; speedup vs baseline: 2.5020x; 1.2809x over previous
//
#include <hip/hip_runtime.h>
#include <math.h>

#define Bsz 8
#define Nn 1024
#define Ff 512
#define Hh 4
#define Dd 128

typedef float f32x4 __attribute__((ext_vector_type(4)));
typedef short bf16x8 __attribute__((ext_vector_type(8)));

__device__ inline uint f2b1(float a) {
    union { float f; uint u; } v; v.f = a;
    return (v.u + 0x7fffu + ((v.u >> 16) & 1u)) >> 16;   // RNE f32->bf16
}
__device__ inline uint f2b_pk(float a, float b) { return f2b1(a) | (f2b1(b) << 16); }

// hT2 layout: el = ((b*32 + (j>>5))*512 + hd)*32 + (j&31)  -- j-tile-blocked, hd-major
// Wc layout:  el = (((nc*64 + kblk)*8 + nt)*16 + n15)*8 + k7

// ============ Kernel 0: pre-swizzle X and W into fragment-major bf16 ============
__global__ __launch_bounds__(256) void conv_xw(const float* __restrict__ X,
                                               const float* __restrict__ Wm,
                                               ushort* __restrict__ Xc,
                                               ushort* __restrict__ Wc) {
    const int bi = blockIdx.x, tid = threadIdx.x;
    if (bi < 512) {
        const int mtile = bi, kblk = tid >> 2, m15b = (tid & 3) * 4;
        #pragma unroll
        for (int c = 0; c < 4; ++c) {
            int m15 = m15b + c;
            const float4* xp = (const float4*)(X + (size_t)(mtile * 16 + m15) * Ff + kblk * 8);
            float4 f0 = xp[0], f1 = xp[1];
            uint4 o = { f2b_pk(f0.x, f0.y), f2b_pk(f0.z, f0.w),
                        f2b_pk(f1.x, f1.y), f2b_pk(f1.z, f1.w) };
            *(uint4*)(Xc + (((size_t)(mtile * 64 + kblk) * 16 + m15) << 3)) = o;
        }
    } else {
        int id = (bi - 512) * 256 + tid;
        int n15 = id & 15, nt = (id >> 4) & 7, kblk = (id >> 7) & 63, nc = id >> 13;
        int col = nc * 128 + nt * 16 + n15;
        float v[8];
        #pragma unroll
        for (int u = 0; u < 8; ++u)
            v[u] = Wm[(size_t)(kblk * 8 + u) * Ff + col];
        uint4 o = { f2b_pk(v[0], v[1]), f2b_pk(v[2], v[3]),
                    f2b_pk(v[4], v[5]), f2b_pk(v[6], v[7]) };
        *(uint4*)(Wc + ((size_t)id << 3)) = o;
    }
}

// ============ Kernel 1: zero-LDS GEMM hT2 = (x@W)^T + e_i/e_j partials ============
// Grid 1024: b = idx&7; mi = (idx>>3)&15 (64-row group); nq = idx>>7 (0..7): head nc=nq>>1,
// half nh=nq&1 (64 hd). 4 blocks/CU, 16 waves/CU. One-step A/B register prefetch.
__global__ __launch_bounds__(256, 4) void gemm_xw(const ushort* __restrict__ Xc,
                                                  const ushort* __restrict__ Wc,
                                                  const float* __restrict__ a_src,
                                                  const float* __restrict__ a_dst,
                                                  ushort* __restrict__ hT,
                                                  float* __restrict__ ei,
                                                  float* __restrict__ ej) {
    const int idx = blockIdx.x;
    const int b = idx & 7, mi = (idx >> 3) & 15, nq = idx >> 7;
    const int nc = nq >> 1, nh = nq & 1;
    const int tid = threadIdx.x;
    const int w = tid >> 6, lane = tid & 63, quad = lane >> 4, l16 = lane & 15;
    const int mtile = (b * 16 + mi) * 4 + w;

    f32x4 z = {0.f, 0.f, 0.f, 0.f};
    f32x4 acc[4];
    #pragma unroll
    for (int t = 0; t < 4; ++t) acc[t] = z;

    const ushort* ap = Xc + ((size_t)mtile << 13) + quad * 128 + l16 * 8;
    const ushort* bp = Wc + ((size_t)nc << 16) + nh * 512 + quad * 1024 + l16 * 8;

    bf16x8 ac = *(const bf16x8*)(ap);
    bf16x8 bc[4];
    #pragma unroll
    for (int t = 0; t < 4; ++t) bc[t] = *(const bf16x8*)(bp + t * 128);

    #pragma unroll 4
    for (int s = 0; s < 16; ++s) {
        bf16x8 an, bn[4];
        if (s < 15) {
            an = *(const bf16x8*)(ap + (s + 1) * 512);
            #pragma unroll
            for (int t = 0; t < 4; ++t)
                bn[t] = *(const bf16x8*)(bp + (s + 1) * 4096 + t * 128);
        }
        #pragma unroll
        for (int t = 0; t < 4; ++t)
            acc[t] = __builtin_amdgcn_mfma_f32_16x16x32_bf16(ac, bc[t], acc[t], 0, 0, 0);
        if (s < 15) {
            ac = an;
            #pragma unroll
            for (int t = 0; t < 4; ++t) bc[t] = bn[t];
        }
    }

    // epilogue 1: hT2 store
    const int nseq = (mi * 4 + w) * 16 + quad * 4;
    const int jb = nseq >> 5, js = nseq & 31;
    #pragma unroll
    for (int t = 0; t < 4; ++t) {
        uint2 pv;
        pv.x = f2b_pk(acc[t][0], acc[t][1]);
        pv.y = f2b_pk(acc[t][2], acc[t][3]);
        int hd = nc * 128 + (nh * 4 + t) * 16 + l16;
        *(uint2*)(hT + ((size_t)(b * 32 + jb)) * 16384 + (size_t)hd * 32 + js) = pv;
    }

    // epilogue 2: e_i/e_j half-head partials (2 exactly-commutative atomics per row)
    {
        float as4[4], ad4[4];
        #pragma unroll
        for (int t = 0; t < 4; ++t) {
            int hd = nc * 128 + (nh * 4 + t) * 16 + l16;
            as4[t] = a_src[hd];
            ad4[t] = a_dst[hd];
        }
        #pragma unroll
        for (int rr = 0; rr < 4; ++rr) {
            float v1 = 0.f, v2 = 0.f;
            #pragma unroll
            for (int t = 0; t < 4; ++t) {
                v1 += acc[t][rr] * as4[t];
                v2 += acc[t][rr] * ad4[t];
            }
            #pragma unroll
            for (int off = 1; off < 16; off <<= 1) {
                v1 += __shfl_xor(v1, off);
                v2 += __shfl_xor(v2, off);
            }
            if (l16 == 0) {
                int n = nseq + rr;
                atomicAdd(ei + ((b * 4 + nc) << 10) + n, v1);
                atomicAdd(ej + ((b * 4 + nc) << 10) + n, v2);
            }
        }
    }
}

// ============ Kernel 2: attention + PV MFMA + residual + LayerNorm ============
// 512 thr = 8 waves: head w&3, j-half w>>2. 32 i-rows/block (two A-frags per wave).
// Grid 256 (32 i-blocks x 8 b), 1 block/CU. jh-partials merged via LDS.
__global__ __launch_bounds__(512, 2) void attn_pv(const ushort* __restrict__ hT,
                                                  const float* __restrict__ ei_g,
                                                  const float* __restrict__ ej_g,
                                                  const int* __restrict__ mask,
                                                  const float* __restrict__ X,
                                                  const float* __restrict__ gamma,
                                                  const float* __restrict__ beta,
                                                  float* __restrict__ out) {
    __shared__ float s_ep[32 * 516];   // 66 KB: partial/merged PV tile [32 i][512 f]
    __shared__ float s_as[4][32];      // partner asum staging

    const int idx = blockIdx.x;
    const int b = idx & 7, i0 = (idx >> 3) * 32;
    const int tid = threadIdx.x;
    const int w = tid >> 6, w4 = w & 3, jh = w >> 2;
    const int lane = tid & 63, quad = lane >> 4, l16 = lane & 15;

    const float* ejh = ej_g + ((b * 4 + w4) << 10);
    const int* mkb = mask + (b << 10);

    // per-head max_j e_j over FULL row (identical for both jh -> consistent shift)
    float maxej = -3.0e38f;
    #pragma unroll
    for (int k = 0; k < 16; ++k) maxej = fmaxf(maxej, ejh[lane + 64 * k]);
    #pragma unroll
    for (int off = 1; off < 64; off <<= 1) maxej = fmaxf(maxej, __shfl_xor(maxej, off));

    // two i-rows per lane: i0+l16 (tile 0), i0+16+l16 (tile 1)
    const float ei0 = ei_g[((b * 4 + w4) << 10) + i0 + l16];
    const float ei1 = ei_g[((b * 4 + w4) << 10) + i0 + 16 + l16];
    const int mi0 = mkb[i0 + l16];
    const int mi1 = mkb[i0 + 16 + l16];
    float m0, m1;
    { float t = ei0 + maxej; m0 = mi0 ? fmaxf(t, 0.2f * t) : -1e9f; }
    { float t = ei1 + maxej; m1 = mi1 ? fmaxf(t, 0.2f * t) : -1e9f; }

    f32x4 z = {0.f, 0.f, 0.f, 0.f};
    f32x4 acc[2][8], asum[2];
    #pragma unroll
    for (int it = 0; it < 2; ++it) { asum[it] = z;
        #pragma unroll
        for (int dt = 0; dt < 8; ++dt) acc[it][dt] = z; }
    bf16x8 ones;
    #pragma unroll
    for (int q = 0; q < 8; ++q) ones[q] = (short)0x3F80;   // bf16 1.0

    const ushort* hTb = hT + ((size_t)(b * 32)) * 16384 + (size_t)(w4 * 128) * 32
                        + l16 * 32 + quad * 8;

    // prefetch step 0 B-fragments
    bf16x8 cur[8];
    {
        const ushort* h0 = hTb + (size_t)(jh * 16) * 16384;
        #pragma unroll
        for (int dt = 0; dt < 8; ++dt) cur[dt] = *(const bf16x8*)(h0 + dt * 512);
    }

    #pragma unroll 2
    for (int r = 0; r < 16; ++r) {
        bf16x8 nxt[8];
        if (r < 15) {
            const ushort* hn = hTb + (size_t)(jh * 16 + r + 1) * 16384;
            #pragma unroll
            for (int dt = 0; dt < 8; ++dt) nxt[dt] = *(const bf16x8*)(hn + dt * 512);
        }
        const int jq = (jh * 16 + r) * 32 + quad * 8;
        float4 e0 = *(const float4*)(ejh + jq);
        float4 e1 = *(const float4*)(ejh + jq + 4);
        int4 q0 = *(const int4*)(mkb + jq);
        int4 q1 = *(const int4*)(mkb + jq + 4);
        float ev[8] = {e0.x, e0.y, e0.z, e0.w, e1.x, e1.y, e1.z, e1.w};
        int   mv[8] = {q0.x, q0.y, q0.z, q0.w, q1.x, q1.y, q1.z, q1.w};
        float wv0[8], wv1[8];
        #pragma unroll
        for (int u = 0; u < 8; ++u) {
            float t0 = ei0 + ev[u];
            float l0 = fmaxf(t0, 0.2f * t0);
            wv0[u] = __expf(((mi0 && mv[u]) ? l0 : -1e9f) - m0);
            float t1 = ei1 + ev[u];
            float l1 = fmaxf(t1, 0.2f * t1);
            wv1[u] = __expf(((mi1 && mv[u]) ? l1 : -1e9f) - m1);
        }
        union { uint4 u; bf16x8 v; } af0, af1;
        af0.u.x = f2b_pk(wv0[0], wv0[1]); af0.u.y = f2b_pk(wv0[2], wv0[3]);
        af0.u.z = f2b_pk(wv0[4], wv0[5]); af0.u.w = f2b_pk(wv0[6], wv0[7]);
        af1.u.x = f2b_pk(wv1[0], wv1[1]); af1.u.y = f2b_pk(wv1[2], wv1[3]);
        af1.u.z = f2b_pk(wv1[4], wv1[5]); af1.u.w = f2b_pk(wv1[6], wv1[7]);
        asum[0] = __builtin_amdgcn_mfma_f32_16x16x32_bf16(af0.v, ones, asum[0], 0, 0, 0);
        asum[1] = __builtin_amdgcn_mfma_f32_16x16x32_bf16(af1.v, ones, asum[1], 0, 0, 0);
        #pragma unroll
        for (int dt = 0; dt < 8; ++dt) {
            acc[0][dt] = __builtin_amdgcn_mfma_f32_16x16x32_bf16(af0.v, cur[dt], acc[0][dt], 0, 0, 0);
            acc[1][dt] = __builtin_amdgcn_mfma_f32_16x16x32_bf16(af1.v, cur[dt], acc[1][dt], 0, 0, 0);
        }
        if (r < 15) {
            #pragma unroll
            for (int dt = 0; dt < 8; ++dt) cur[dt] = nxt[dt];
        }
    }

    // merge jh halves via LDS, then normalize
    if (jh == 1) {
        #pragma unroll
        for (int it = 0; it < 2; ++it)
            #pragma unroll
            for (int dt = 0; dt < 8; ++dt)
                #pragma unroll
                for (int rr = 0; rr < 4; ++rr)
                    s_ep[(it * 16 + quad * 4 + rr) * 516 + w4 * 128 + dt * 16 + l16] =
                        acc[it][dt][rr];
        if (l16 == 0) {
            #pragma unroll
            for (int it = 0; it < 2; ++it)
                #pragma unroll
                for (int rr = 0; rr < 4; ++rr)
                    s_as[w4][it * 16 + quad * 4 + rr] = asum[it][rr];
        }
    }
    __syncthreads();
    if (jh == 0) {
        float rs[2][4];
        #pragma unroll
        for (int it = 0; it < 2; ++it)
            #pragma unroll
            for (int rr = 0; rr < 4; ++rr)
                rs[it][rr] = 1.f / (asum[it][rr] + s_as[w4][it * 16 + quad * 4 + rr]);
        #pragma unroll
        for (int it = 0; it < 2; ++it)
            #pragma unroll
            for (int dt = 0; dt < 8; ++dt)
                #pragma unroll
                for (int rr = 0; rr < 4; ++rr) {
                    int off = (it * 16 + quad * 4 + rr) * 516 + w4 * 128 + dt * 16 + l16;
                    s_ep[off] = (acc[it][dt][rr] + s_ep[off]) * rs[it][rr];
                }
    }
    __syncthreads();

    // residual + LayerNorm: 8 waves x 4 rows = 32 rows
    #pragma unroll
    for (int q = 0; q < 4; ++q) {
        int ir = w * 4 + q;
        int ig = i0 + ir;
        float4 p0 = *(const float4*)(&s_ep[ir * 516 + lane * 8]);
        float4 p1 = *(const float4*)(&s_ep[ir * 516 + lane * 8 + 4]);
        const float* xp = X + (((size_t)((b << 10) + ig)) << 9) + lane * 8;
        float4 x0 = *(const float4*)(xp);
        float4 x1 = *(const float4*)(xp + 4);
        float v[8] = {p0.x + x0.x, p0.y + x0.y, p0.z + x0.z, p0.w + x0.w,
                      p1.x + x1.x, p1.y + x1.y, p1.z + x1.z, p1.w + x1.w};
        float s1 = 0.f, s2 = 0.f;
        #pragma unroll
        for (int u = 0; u < 8; ++u) { s1 += v[u]; s2 += v[u] * v[u]; }
        #pragma unroll
        for (int off = 1; off < 64; off <<= 1) { s1 += __shfl_xor(s1, off); s2 += __shfl_xor(s2, off); }
        float mean = s1 * (1.f / 512.f);
        float var  = s2 * (1.f / 512.f) - mean * mean;
        float rstd = rsqrtf(var + 1e-5f);
        int f0i = lane * 8;
        float4 g0 = *(const float4*)(gamma + f0i);
        float4 g1 = *(const float4*)(gamma + f0i + 4);
        float4 be0 = *(const float4*)(beta + f0i);
        float4 be1 = *(const float4*)(beta + f0i + 4);
        float* op = out + (((size_t)((b << 10) + ig)) << 9) + f0i;
        float4 o0, o1;
        o0.x = (v[0] - mean) * rstd * g0.x + be0.x;
        o0.y = (v[1] - mean) * rstd * g0.y + be0.y;
        o0.z = (v[2] - mean) * rstd * g0.z + be0.z;
        o0.w = (v[3] - mean) * rstd * g0.w + be0.w;
        o1.x = (v[4] - mean) * rstd * g1.x + be1.x;
        o1.y = (v[5] - mean) * rstd * g1.y + be1.y;
        o1.z = (v[6] - mean) * rstd * g1.z + be1.z;
        o1.w = (v[7] - mean) * rstd * g1.w + be1.w;
        *(float4*)op = o0;
        *(float4*)(op + 4) = o1;
    }
}

extern "C" void kernel_launch(void* const* d_in, const int* in_sizes, int n_in,
                              void* d_out, int out_size, void* d_ws, size_t ws_size,
                              hipStream_t stream) {
    const float* x     = (const float*)d_in[0];
    const int*   mask  = (const int*)d_in[1];
    const float* W     = (const float*)d_in[2];
    const float* a_src = (const float*)d_in[3];
    const float* a_dst = (const float*)d_in[4];
    const float* gamma = (const float*)d_in[5];
    const float* beta  = (const float*)d_in[6];
    float* out = (float*)d_out;

    ushort* hT = (ushort*)d_ws;                            // 8 MB
    ushort* Xc = hT + (size_t)8 * 512 * 1024;              // 8 MB
    ushort* Wc = Xc + (size_t)8 * 1024 * 512;              // 0.5 MB
    float* ei = (float*)(Wc + (size_t)512 * 512);          // 128 KB
    float* ej = ei + 32768;

    hipMemsetAsync(ei, 0, 2 * 32768 * sizeof(float), stream);
    conv_xw<<<dim3(640), 256, 0, stream>>>(x, W, Xc, Wc);
    gemm_xw<<<dim3(1024), 256, 0, stream>>>(Xc, Wc, a_src, a_dst, hT, ei, ej);
    attn_pv<<<dim3(256), 512, 0, stream>>>(hT, ei, ej, mask, x, gamma, beta, out);
}

// Round 8
// 131.895 us; speedup vs baseline: 2.5385x; 1.0146x over previous
//
#include <hip/hip_runtime.h>
#include <math.h>

#define Bsz 8
#define Nn 1024
#define Ff 512
#define Hh 4
#define Dd 128

typedef float f32x4 __attribute__((ext_vector_type(4)));
typedef short bf16x8 __attribute__((ext_vector_type(8)));

__device__ inline uint f2b1(float a) {
    union { float f; uint u; } v; v.f = a;
    return (v.u + 0x7fffu + ((v.u >> 16) & 1u)) >> 16;   // RNE f32->bf16
}
__device__ inline uint f2b_pk(float a, float b) { return f2b1(a) | (f2b1(b) << 16); }

// hT2 layout: el = ((b*32 + (j>>5))*512 + hd)*32 + (j&31)  -- j-tile-blocked, hd-major
// Wc layout:  el = (((nc*64 + kblk)*8 + nt)*16 + n15)*8 + k7

// ============ Kernel 0: pre-swizzle X and W into fragment-major bf16 ============
// Blocks 0..511: X part. Blocks 512..575: W part (kblk = bi-512), LDS-transposed.
__global__ __launch_bounds__(256) void conv_xw(const float* __restrict__ X,
                                               const float* __restrict__ Wm,
                                               ushort* __restrict__ Xc,
                                               ushort* __restrict__ Wc) {
    __shared__ float tile[8 * 520];   // [k7][n], pitch 520
    const int bi = blockIdx.x, tid = threadIdx.x;
    if (bi < 512) {
        const int mtile = bi, kblk = tid >> 2, m15b = (tid & 3) * 4;
        #pragma unroll
        for (int c = 0; c < 4; ++c) {
            int m15 = m15b + c;
            const float4* xp = (const float4*)(X + (size_t)(mtile * 16 + m15) * Ff + kblk * 8);
            float4 f0 = xp[0], f1 = xp[1];
            uint4 o = { f2b_pk(f0.x, f0.y), f2b_pk(f0.z, f0.w),
                        f2b_pk(f1.x, f1.y), f2b_pk(f1.z, f1.w) };
            *(uint4*)(Xc + (((size_t)(mtile * 64 + kblk) * 16 + m15) << 3)) = o;
        }
    } else {
        // W part: this block handles k rows kb*8..kb*8+7, all 512 n.
        const int kb = bi - 512;
        const int l = tid & 63, wv = tid >> 6;     // lane -> col group, wave -> k row
        const int col0 = l * 8;
        #pragma unroll
        for (int rsel = 0; rsel < 2; ++rsel) {
            int kr = wv + rsel * 4;                // 0..7
            const float4* wp = (const float4*)(Wm + (size_t)(kb * 8 + kr) * Ff + col0);
            float4 a = wp[0], c = wp[1];
            *(float4*)(&tile[kr * 520 + col0]) = a;
            *(float4*)(&tile[kr * 520 + col0 + 4]) = c;
        }
        __syncthreads();
        #pragma unroll
        for (int rsel = 0; rsel < 2; ++rsel) {
            int n = tid + rsel * 256;              // 0..511 == nc*128 + nt*16 + n15
            float v[8];
            #pragma unroll
            for (int u = 0; u < 8; ++u) v[u] = tile[u * 520 + n];
            uint4 o = { f2b_pk(v[0], v[1]), f2b_pk(v[2], v[3]),
                        f2b_pk(v[4], v[5]), f2b_pk(v[6], v[7]) };
            int nc = n >> 7, nt = (n >> 4) & 7, n15 = n & 15;
            *(uint4*)(Wc + ((size_t)(((nc * 64 + kb) * 8 + nt) * 16 + n15) << 3)) = o;
        }
    }
}

// ============ Kernel 1: zero-LDS GEMM hT2 = (x@W)^T + exact e_i/e_j ============
// Grid 512: b = idx&7, mi = (idx>>3)&15 (64 m-rows), nc = idx>>7 (head, 128 hd).
// 2 blocks/CU. One-step register prefetch: 9 loads issued under 8 MFMAs.
__global__ __launch_bounds__(256, 4) void gemm_xw(const ushort* __restrict__ Xc,
                                                  const ushort* __restrict__ Wc,
                                                  const float* __restrict__ a_src,
                                                  const float* __restrict__ a_dst,
                                                  ushort* __restrict__ hT,
                                                  float* __restrict__ ei,
                                                  float* __restrict__ ej) {
    const int idx = blockIdx.x;
    const int b = idx & 7, sub = idx >> 3;
    const int mi = sub & 15, nc = sub >> 4;
    const int tid = threadIdx.x;
    const int w = tid >> 6, lane = tid & 63, quad = lane >> 4, l16 = lane & 15;
    const int mtile = (b * 16 + mi) * 4 + w;

    f32x4 z = {0.f, 0.f, 0.f, 0.f};
    f32x4 acc[8];
    #pragma unroll
    for (int nt = 0; nt < 8; ++nt) acc[nt] = z;

    const ushort* ap = Xc + ((size_t)mtile << 13) + quad * 128 + l16 * 8;
    const ushort* bp = Wc + ((size_t)nc << 16) + quad * 1024 + l16 * 8;

    bf16x8 ac = *(const bf16x8*)(ap);
    bf16x8 bc[8];
    #pragma unroll
    for (int nt = 0; nt < 8; ++nt) bc[nt] = *(const bf16x8*)(bp + nt * 128);

    #pragma unroll 2
    for (int s = 0; s < 16; ++s) {
        bf16x8 an, bn[8];
        if (s < 15) {
            an = *(const bf16x8*)(ap + (s + 1) * 512);
            #pragma unroll
            for (int nt = 0; nt < 8; ++nt)
                bn[nt] = *(const bf16x8*)(bp + (s + 1) * 4096 + nt * 128);
        }
        #pragma unroll
        for (int nt = 0; nt < 8; ++nt)
            acc[nt] = __builtin_amdgcn_mfma_f32_16x16x32_bf16(ac, bc[nt], acc[nt], 0, 0, 0);
        if (s < 15) {
            ac = an;
            #pragma unroll
            for (int nt = 0; nt < 8; ++nt) bc[nt] = bn[nt];
        }
    }

    // epilogue 1: hT2 store
    const int nseq = (mi * 4 + w) * 16 + quad * 4;
    const int jb = nseq >> 5, js = nseq & 31;
    #pragma unroll
    for (int nt = 0; nt < 8; ++nt) {
        uint2 pv;
        pv.x = f2b_pk(acc[nt][0], acc[nt][1]);
        pv.y = f2b_pk(acc[nt][2], acc[nt][3]);
        int hd = nc * 128 + nt * 16 + l16;
        *(uint2*)(hT + ((size_t)(b * 32 + jb)) * 16384 + (size_t)hd * 32 + js) = pv;
    }

    // epilogue 2: exact e_i/e_j (full head in this block), no atomics
    {
        float as4[8], ad4[8];
        #pragma unroll
        for (int nt = 0; nt < 8; ++nt) {
            as4[nt] = a_src[nc * 128 + nt * 16 + l16];
            ad4[nt] = a_dst[nc * 128 + nt * 16 + l16];
        }
        #pragma unroll
        for (int rr = 0; rr < 4; ++rr) {
            float v1 = 0.f, v2 = 0.f;
            #pragma unroll
            for (int nt = 0; nt < 8; ++nt) {
                v1 += acc[nt][rr] * as4[nt];
                v2 += acc[nt][rr] * ad4[nt];
            }
            #pragma unroll
            for (int off = 1; off < 16; off <<= 1) {
                v1 += __shfl_xor(v1, off);
                v2 += __shfl_xor(v2, off);
            }
            if (l16 == 0) {
                int n = nseq + rr;
                ei[((b * 4 + nc) << 10) + n] = v1;
                ej[((b * 4 + nc) << 10) + n] = v2;
            }
        }
    }
}

// ============ Kernel 2: attention + PV MFMA + residual + LayerNorm ============
// (byte-identical to R7's verified attn_pv)
__global__ __launch_bounds__(512, 2) void attn_pv(const ushort* __restrict__ hT,
                                                  const float* __restrict__ ei_g,
                                                  const float* __restrict__ ej_g,
                                                  const int* __restrict__ mask,
                                                  const float* __restrict__ X,
                                                  const float* __restrict__ gamma,
                                                  const float* __restrict__ beta,
                                                  float* __restrict__ out) {
    __shared__ float s_ep[32 * 516];
    __shared__ float s_as[4][32];

    const int idx = blockIdx.x;
    const int b = idx & 7, i0 = (idx >> 3) * 32;
    const int tid = threadIdx.x;
    const int w = tid >> 6, w4 = w & 3, jh = w >> 2;
    const int lane = tid & 63, quad = lane >> 4, l16 = lane & 15;

    const float* ejh = ej_g + ((b * 4 + w4) << 10);
    const int* mkb = mask + (b << 10);

    float maxej = -3.0e38f;
    #pragma unroll
    for (int k = 0; k < 16; ++k) maxej = fmaxf(maxej, ejh[lane + 64 * k]);
    #pragma unroll
    for (int off = 1; off < 64; off <<= 1) maxej = fmaxf(maxej, __shfl_xor(maxej, off));

    const float ei0 = ei_g[((b * 4 + w4) << 10) + i0 + l16];
    const float ei1 = ei_g[((b * 4 + w4) << 10) + i0 + 16 + l16];
    const int mi0 = mkb[i0 + l16];
    const int mi1 = mkb[i0 + 16 + l16];
    float m0, m1;
    { float t = ei0 + maxej; m0 = mi0 ? fmaxf(t, 0.2f * t) : -1e9f; }
    { float t = ei1 + maxej; m1 = mi1 ? fmaxf(t, 0.2f * t) : -1e9f; }

    f32x4 z = {0.f, 0.f, 0.f, 0.f};
    f32x4 acc[2][8], asum[2];
    #pragma unroll
    for (int it = 0; it < 2; ++it) { asum[it] = z;
        #pragma unroll
        for (int dt = 0; dt < 8; ++dt) acc[it][dt] = z; }
    bf16x8 ones;
    #pragma unroll
    for (int q = 0; q < 8; ++q) ones[q] = (short)0x3F80;

    const ushort* hTb = hT + ((size_t)(b * 32)) * 16384 + (size_t)(w4 * 128) * 32
                        + l16 * 32 + quad * 8;

    bf16x8 cur[8];
    {
        const ushort* h0 = hTb + (size_t)(jh * 16) * 16384;
        #pragma unroll
        for (int dt = 0; dt < 8; ++dt) cur[dt] = *(const bf16x8*)(h0 + dt * 512);
    }

    #pragma unroll 2
    for (int r = 0; r < 16; ++r) {
        bf16x8 nxt[8];
        if (r < 15) {
            const ushort* hn = hTb + (size_t)(jh * 16 + r + 1) * 16384;
            #pragma unroll
            for (int dt = 0; dt < 8; ++dt) nxt[dt] = *(const bf16x8*)(hn + dt * 512);
        }
        const int jq = (jh * 16 + r) * 32 + quad * 8;
        float4 e0 = *(const float4*)(ejh + jq);
        float4 e1 = *(const float4*)(ejh + jq + 4);
        int4 q0 = *(const int4*)(mkb + jq);
        int4 q1 = *(const int4*)(mkb + jq + 4);
        float ev[8] = {e0.x, e0.y, e0.z, e0.w, e1.x, e1.y, e1.z, e1.w};
        int   mv[8] = {q0.x, q0.y, q0.z, q0.w, q1.x, q1.y, q1.z, q1.w};
        float wv0[8], wv1[8];
        #pragma unroll
        for (int u = 0; u < 8; ++u) {
            float t0 = ei0 + ev[u];
            float l0 = fmaxf(t0, 0.2f * t0);
            wv0[u] = __expf(((mi0 && mv[u]) ? l0 : -1e9f) - m0);
            float t1 = ei1 + ev[u];
            float l1 = fmaxf(t1, 0.2f * t1);
            wv1[u] = __expf(((mi1 && mv[u]) ? l1 : -1e9f) - m1);
        }
        union { uint4 u; bf16x8 v; } af0, af1;
        af0.u.x = f2b_pk(wv0[0], wv0[1]); af0.u.y = f2b_pk(wv0[2], wv0[3]);
        af0.u.z = f2b_pk(wv0[4], wv0[5]); af0.u.w = f2b_pk(wv0[6], wv0[7]);
        af1.u.x = f2b_pk(wv1[0], wv1[1]); af1.u.y = f2b_pk(wv1[2], wv1[3]);
        af1.u.z = f2b_pk(wv1[4], wv1[5]); af1.u.w = f2b_pk(wv1[6], wv1[7]);
        asum[0] = __builtin_amdgcn_mfma_f32_16x16x32_bf16(af0.v, ones, asum[0], 0, 0, 0);
        asum[1] = __builtin_amdgcn_mfma_f32_16x16x32_bf16(af1.v, ones, asum[1], 0, 0, 0);
        #pragma unroll
        for (int dt = 0; dt < 8; ++dt) {
            acc[0][dt] = __builtin_amdgcn_mfma_f32_16x16x32_bf16(af0.v, cur[dt], acc[0][dt], 0, 0, 0);
            acc[1][dt] = __builtin_amdgcn_mfma_f32_16x16x32_bf16(af1.v, cur[dt], acc[1][dt], 0, 0, 0);
        }
        if (r < 15) {
            #pragma unroll
            for (int dt = 0; dt < 8; ++dt) cur[dt] = nxt[dt];
        }
    }

    if (jh == 1) {
        #pragma unroll
        for (int it = 0; it < 2; ++it)
            #pragma unroll
            for (int dt = 0; dt < 8; ++dt)
                #pragma unroll
                for (int rr = 0; rr < 4; ++rr)
                    s_ep[(it * 16 + quad * 4 + rr) * 516 + w4 * 128 + dt * 16 + l16] =
                        acc[it][dt][rr];
        if (l16 == 0) {
            #pragma unroll
            for (int it = 0; it < 2; ++it)
                #pragma unroll
                for (int rr = 0; rr < 4; ++rr)
                    s_as[w4][it * 16 + quad * 4 + rr] = asum[it][rr];
        }
    }
    __syncthreads();
    if (jh == 0) {
        float rs[2][4];
        #pragma unroll
        for (int it = 0; it < 2; ++it)
            #pragma unroll
            for (int rr = 0; rr < 4; ++rr)
                rs[it][rr] = 1.f / (asum[it][rr] + s_as[w4][it * 16 + quad * 4 + rr]);
        #pragma unroll
        for (int it = 0; it < 2; ++it)
            #pragma unroll
            for (int dt = 0; dt < 8; ++dt)
                #pragma unroll
                for (int rr = 0; rr < 4; ++rr) {
                    int off = (it * 16 + quad * 4 + rr) * 516 + w4 * 128 + dt * 16 + l16;
                    s_ep[off] = (acc[it][dt][rr] + s_ep[off]) * rs[it][rr];
                }
    }
    __syncthreads();

    #pragma unroll
    for (int q = 0; q < 4; ++q) {
        int ir = w * 4 + q;
        int ig = i0 + ir;
        float4 p0 = *(const float4*)(&s_ep[ir * 516 + lane * 8]);
        float4 p1 = *(const float4*)(&s_ep[ir * 516 + lane * 8 + 4]);
        const float* xp = X + (((size_t)((b << 10) + ig)) << 9) + lane * 8;
        float4 x0 = *(const float4*)(xp);
        float4 x1 = *(const float4*)(xp + 4);
        float v[8] = {p0.x + x0.x, p0.y + x0.y, p0.z + x0.z, p0.w + x0.w,
                      p1.x + x1.x, p1.y + x1.y, p1.z + x1.z, p1.w + x1.w};
        float s1 = 0.f, s2 = 0.f;
        #pragma unroll
        for (int u = 0; u < 8; ++u) { s1 += v[u]; s2 += v[u] * v[u]; }
        #pragma unroll
        for (int off = 1; off < 64; off <<= 1) { s1 += __shfl_xor(s1, off); s2 += __shfl_xor(s2, off); }
        float mean = s1 * (1.f / 512.f);
        float var  = s2 * (1.f / 512.f) - mean * mean;
        float rstd = rsqrtf(var + 1e-5f);
        int f0i = lane * 8;
        float4 g0 = *(const float4*)(gamma + f0i);
        float4 g1 = *(const float4*)(gamma + f0i + 4);
        float4 be0 = *(const float4*)(beta + f0i);
        float4 be1 = *(const float4*)(beta + f0i + 4);
        float* op = out + (((size_t)((b << 10) + ig)) << 9) + f0i;
        float4 o0, o1;
        o0.x = (v[0] - mean) * rstd * g0.x + be0.x;
        o0.y = (v[1] - mean) * rstd * g0.y + be0.y;
        o0.z = (v[2] - mean) * rstd * g0.z + be0.z;
        o0.w = (v[3] - mean) * rstd * g0.w + be0.w;
        o1.x = (v[4] - mean) * rstd * g1.x + be1.x;
        o1.y = (v[5] - mean) * rstd * g1.y + be1.y;
        o1.z = (v[6] - mean) * rstd * g1.z + be1.z;
        o1.w = (v[7] - mean) * rstd * g1.w + be1.w;
        *(float4*)op = o0;
        *(float4*)(op + 4) = o1;
    }
}

extern "C" void kernel_launch(void* const* d_in, const int* in_sizes, int n_in,
                              void* d_out, int out_size, void* d_ws, size_t ws_size,
                              hipStream_t stream) {
    const float* x     = (const float*)d_in[0];
    const int*   mask  = (const int*)d_in[1];
    const float* W     = (const float*)d_in[2];
    const float* a_src = (const float*)d_in[3];
    const float* a_dst = (const float*)d_in[4];
    const float* gamma = (const float*)d_in[5];
    const float* beta  = (const float*)d_in[6];
    float* out = (float*)d_out;

    ushort* hT = (ushort*)d_ws;                            // 8 MB
    ushort* Xc = hT + (size_t)8 * 512 * 1024;              // 8 MB
    ushort* Wc = Xc + (size_t)8 * 1024 * 512;              // 0.5 MB
    float* ei = (float*)(Wc + (size_t)512 * 512);          // 128 KB
    float* ej = ei + 32768;

    conv_xw<<<dim3(576), 256, 0, stream>>>(x, W, Xc, Wc);
    gemm_xw<<<dim3(512), 256, 0, stream>>>(Xc, Wc, a_src, a_dst, hT, ei, ej);
    attn_pv<<<dim3(256), 512, 0, stream>>>(hT, ei, ej, mask, x, gamma, beta, out);
}

// Round 9
// 125.854 us; speedup vs baseline: 2.6603x; 1.0480x over previous
//
#include <hip/hip_runtime.h>
#include <math.h>

#define Bsz 8
#define Nn 1024
#define Ff 512
#define Hh 4
#define Dd 128

typedef float f32x4 __attribute__((ext_vector_type(4)));
typedef short bf16x8 __attribute__((ext_vector_type(8)));

__device__ inline uint f2b1(float a) {
    union { float f; uint u; } v; v.f = a;
    return (v.u + 0x7fffu + ((v.u >> 16) & 1u)) >> 16;   // RNE f32->bf16
}
__device__ inline uint f2b_pk(float a, float b) { return f2b1(a) | (f2b1(b) << 16); }

// hT2 layout: el = ((b*32 + (j>>5))*512 + hd)*32 + (j&31)  -- j-tile-blocked, hd-major
// Wc layout:  el = (((nc*64 + kblk)*8 + nt)*16 + n15)*8 + k7

// ============ Kernel 0: pre-swizzle X and W into fragment-major bf16 ============
// X-part blocks 0..511: b = bi&7 (XCD-matched with gemm consumer), mtile = b*64 + (bi>>3).
// W-part blocks 512..575: kblk = bi-512, LDS-transposed.
__global__ __launch_bounds__(256) void conv_xw(const float* __restrict__ X,
                                               const float* __restrict__ Wm,
                                               ushort* __restrict__ Xc,
                                               ushort* __restrict__ Wc) {
    __shared__ float tile[8 * 520];   // [k7][n], pitch 520
    const int bi = blockIdx.x, tid = threadIdx.x;
    if (bi < 512) {
        const int mtile = (bi & 7) * 64 + (bi >> 3);   // XCD-matched producer mapping
        const int kblk = tid >> 2, m15b = (tid & 3) * 4;
        #pragma unroll
        for (int c = 0; c < 4; ++c) {
            int m15 = m15b + c;
            const float4* xp = (const float4*)(X + (size_t)(mtile * 16 + m15) * Ff + kblk * 8);
            float4 f0 = xp[0], f1 = xp[1];
            uint4 o = { f2b_pk(f0.x, f0.y), f2b_pk(f0.z, f0.w),
                        f2b_pk(f1.x, f1.y), f2b_pk(f1.z, f1.w) };
            *(uint4*)(Xc + (((size_t)(mtile * 64 + kblk) * 16 + m15) << 3)) = o;
        }
    } else {
        const int kb = bi - 512;
        const int l = tid & 63, wv = tid >> 6;
        const int col0 = l * 8;
        #pragma unroll
        for (int rsel = 0; rsel < 2; ++rsel) {
            int kr = wv + rsel * 4;
            const float4* wp = (const float4*)(Wm + (size_t)(kb * 8 + kr) * Ff + col0);
            float4 a = wp[0], c = wp[1];
            *(float4*)(&tile[kr * 520 + col0]) = a;
            *(float4*)(&tile[kr * 520 + col0 + 4]) = c;
        }
        __syncthreads();
        #pragma unroll
        for (int rsel = 0; rsel < 2; ++rsel) {
            int n = tid + rsel * 256;
            float v[8];
            #pragma unroll
            for (int u = 0; u < 8; ++u) v[u] = tile[u * 520 + n];
            uint4 o = { f2b_pk(v[0], v[1]), f2b_pk(v[2], v[3]),
                        f2b_pk(v[4], v[5]), f2b_pk(v[6], v[7]) };
            int nc = n >> 7, nt = (n >> 4) & 7, n15 = n & 15;
            *(uint4*)(Wc + ((size_t)(((nc * 64 + kb) * 8 + nt) * 16 + n15) << 3)) = o;
        }
    }
}

// ============ Kernel 1: zero-LDS GEMM hT2 = (x@W)^T + exact e_i/e_j ============
// Grid 512: b = idx&7, mi = (idx>>3)&15, nc = idx>>7. 2 blocks/CU. Prefetch depth 2.
__global__ __launch_bounds__(256, 2) void gemm_xw(const ushort* __restrict__ Xc,
                                                  const ushort* __restrict__ Wc,
                                                  const float* __restrict__ a_src,
                                                  const float* __restrict__ a_dst,
                                                  ushort* __restrict__ hT,
                                                  float* __restrict__ ei,
                                                  float* __restrict__ ej) {
    const int idx = blockIdx.x;
    const int b = idx & 7, sub = idx >> 3;
    const int mi = sub & 15, nc = sub >> 4;
    const int tid = threadIdx.x;
    const int w = tid >> 6, lane = tid & 63, quad = lane >> 4, l16 = lane & 15;
    const int mtile = (b * 16 + mi) * 4 + w;

    f32x4 z = {0.f, 0.f, 0.f, 0.f};
    f32x4 acc[8];
    #pragma unroll
    for (int nt = 0; nt < 8; ++nt) acc[nt] = z;

    const ushort* ap = Xc + ((size_t)mtile << 13) + quad * 128 + l16 * 8;
    const ushort* bp = Wc + ((size_t)nc << 16) + quad * 1024 + l16 * 8;

    bf16x8 ab[2];
    bf16x8 bb[2][8];
    ab[0] = *(const bf16x8*)(ap);
    ab[1] = *(const bf16x8*)(ap + 512);
    #pragma unroll
    for (int nt = 0; nt < 8; ++nt) {
        bb[0][nt] = *(const bf16x8*)(bp + nt * 128);
        bb[1][nt] = *(const bf16x8*)(bp + 4096 + nt * 128);
    }

    #pragma unroll 2
    for (int s = 0; s < 16; ++s) {
        const int c = s & 1;
        #pragma unroll
        for (int nt = 0; nt < 8; ++nt)
            acc[nt] = __builtin_amdgcn_mfma_f32_16x16x32_bf16(ab[c], bb[c][nt], acc[nt], 0, 0, 0);
        if (s + 2 < 16) {   // reload slot c for step s+2 (regs already consumed)
            ab[c] = *(const bf16x8*)(ap + (s + 2) * 512);
            #pragma unroll
            for (int nt = 0; nt < 8; ++nt)
                bb[c][nt] = *(const bf16x8*)(bp + (s + 2) * 4096 + nt * 128);
        }
    }

    // epilogue 1: hT2 store
    const int nseq = (mi * 4 + w) * 16 + quad * 4;
    const int jb = nseq >> 5, js = nseq & 31;
    #pragma unroll
    for (int nt = 0; nt < 8; ++nt) {
        uint2 pv;
        pv.x = f2b_pk(acc[nt][0], acc[nt][1]);
        pv.y = f2b_pk(acc[nt][2], acc[nt][3]);
        int hd = nc * 128 + nt * 16 + l16;
        *(uint2*)(hT + ((size_t)(b * 32 + jb)) * 16384 + (size_t)hd * 32 + js) = pv;
    }

    // epilogue 2: exact e_i/e_j (full head in this block), no atomics
    {
        float as4[8], ad4[8];
        #pragma unroll
        for (int nt = 0; nt < 8; ++nt) {
            as4[nt] = a_src[nc * 128 + nt * 16 + l16];
            ad4[nt] = a_dst[nc * 128 + nt * 16 + l16];
        }
        #pragma unroll
        for (int rr = 0; rr < 4; ++rr) {
            float v1 = 0.f, v2 = 0.f;
            #pragma unroll
            for (int nt = 0; nt < 8; ++nt) {
                v1 += acc[nt][rr] * as4[nt];
                v2 += acc[nt][rr] * ad4[nt];
            }
            #pragma unroll
            for (int off = 1; off < 16; off <<= 1) {
                v1 += __shfl_xor(v1, off);
                v2 += __shfl_xor(v2, off);
            }
            if (l16 == 0) {
                int n = nseq + rr;
                ei[((b * 4 + nc) << 10) + n] = v1;
                ej[((b * 4 + nc) << 10) + n] = v2;
            }
        }
    }
}

// ============ Kernel 2: attention + PV MFMA + residual + LayerNorm ============
// 512 thr = 8 waves: head w&3, j-half w>>2. 32 i-rows/block. Grid 256. Prefetch depth 2.
__global__ __launch_bounds__(512, 2) void attn_pv(const ushort* __restrict__ hT,
                                                  const float* __restrict__ ei_g,
                                                  const float* __restrict__ ej_g,
                                                  const int* __restrict__ mask,
                                                  const float* __restrict__ X,
                                                  const float* __restrict__ gamma,
                                                  const float* __restrict__ beta,
                                                  float* __restrict__ out) {
    __shared__ float s_ep[32 * 516];
    __shared__ float s_as[4][32];

    const int idx = blockIdx.x;
    const int b = idx & 7, i0 = (idx >> 3) * 32;
    const int tid = threadIdx.x;
    const int w = tid >> 6, w4 = w & 3, jh = w >> 2;
    const int lane = tid & 63, quad = lane >> 4, l16 = lane & 15;

    const float* ejh = ej_g + ((b * 4 + w4) << 10);
    const int* mkb = mask + (b << 10);

    float maxej = -3.0e38f;
    #pragma unroll
    for (int k = 0; k < 16; ++k) maxej = fmaxf(maxej, ejh[lane + 64 * k]);
    #pragma unroll
    for (int off = 1; off < 64; off <<= 1) maxej = fmaxf(maxej, __shfl_xor(maxej, off));

    const float ei0 = ei_g[((b * 4 + w4) << 10) + i0 + l16];
    const float ei1 = ei_g[((b * 4 + w4) << 10) + i0 + 16 + l16];
    const int mi0 = mkb[i0 + l16];
    const int mi1 = mkb[i0 + 16 + l16];
    float m0, m1;
    { float t = ei0 + maxej; m0 = mi0 ? fmaxf(t, 0.2f * t) : -1e9f; }
    { float t = ei1 + maxej; m1 = mi1 ? fmaxf(t, 0.2f * t) : -1e9f; }

    f32x4 z = {0.f, 0.f, 0.f, 0.f};
    f32x4 acc[2][8], asum[2];
    #pragma unroll
    for (int it = 0; it < 2; ++it) { asum[it] = z;
        #pragma unroll
        for (int dt = 0; dt < 8; ++dt) acc[it][dt] = z; }
    bf16x8 ones;
    #pragma unroll
    for (int q = 0; q < 8; ++q) ones[q] = (short)0x3F80;

    const ushort* hTb = hT + ((size_t)(b * 32)) * 16384 + (size_t)(w4 * 128) * 32
                        + l16 * 32 + quad * 8;

    // prefetch steps 0 and 1
    bf16x8 B[2][8];
    #pragma unroll
    for (int c = 0; c < 2; ++c) {
        const ushort* h0 = hTb + (size_t)(jh * 16 + c) * 16384;
        #pragma unroll
        for (int dt = 0; dt < 8; ++dt) B[c][dt] = *(const bf16x8*)(h0 + dt * 512);
    }

    #pragma unroll 2
    for (int r = 0; r < 16; ++r) {
        const int c = r & 1;
        const int jq = (jh * 16 + r) * 32 + quad * 8;
        float4 e0 = *(const float4*)(ejh + jq);
        float4 e1 = *(const float4*)(ejh + jq + 4);
        int4 q0 = *(const int4*)(mkb + jq);
        int4 q1 = *(const int4*)(mkb + jq + 4);
        float ev[8] = {e0.x, e0.y, e0.z, e0.w, e1.x, e1.y, e1.z, e1.w};
        int   mv[8] = {q0.x, q0.y, q0.z, q0.w, q1.x, q1.y, q1.z, q1.w};
        float wv0[8], wv1[8];
        #pragma unroll
        for (int u = 0; u < 8; ++u) {
            float t0 = ei0 + ev[u];
            float l0 = fmaxf(t0, 0.2f * t0);
            wv0[u] = __expf(((mi0 && mv[u]) ? l0 : -1e9f) - m0);
            float t1 = ei1 + ev[u];
            float l1 = fmaxf(t1, 0.2f * t1);
            wv1[u] = __expf(((mi1 && mv[u]) ? l1 : -1e9f) - m1);
        }
        union { uint4 u; bf16x8 v; } af0, af1;
        af0.u.x = f2b_pk(wv0[0], wv0[1]); af0.u.y = f2b_pk(wv0[2], wv0[3]);
        af0.u.z = f2b_pk(wv0[4], wv0[5]); af0.u.w = f2b_pk(wv0[6], wv0[7]);
        af1.u.x = f2b_pk(wv1[0], wv1[1]); af1.u.y = f2b_pk(wv1[2], wv1[3]);
        af1.u.z = f2b_pk(wv1[4], wv1[5]); af1.u.w = f2b_pk(wv1[6], wv1[7]);
        asum[0] = __builtin_amdgcn_mfma_f32_16x16x32_bf16(af0.v, ones, asum[0], 0, 0, 0);
        asum[1] = __builtin_amdgcn_mfma_f32_16x16x32_bf16(af1.v, ones, asum[1], 0, 0, 0);
        #pragma unroll
        for (int dt = 0; dt < 8; ++dt) {
            acc[0][dt] = __builtin_amdgcn_mfma_f32_16x16x32_bf16(af0.v, B[c][dt], acc[0][dt], 0, 0, 0);
            acc[1][dt] = __builtin_amdgcn_mfma_f32_16x16x32_bf16(af1.v, B[c][dt], acc[1][dt], 0, 0, 0);
        }
        if (r + 2 < 16) {   // reload slot c for step r+2
            const ushort* hn = hTb + (size_t)(jh * 16 + r + 2) * 16384;
            #pragma unroll
            for (int dt = 0; dt < 8; ++dt) B[c][dt] = *(const bf16x8*)(hn + dt * 512);
        }
    }

    if (jh == 1) {
        #pragma unroll
        for (int it = 0; it < 2; ++it)
            #pragma unroll
            for (int dt = 0; dt < 8; ++dt)
                #pragma unroll
                for (int rr = 0; rr < 4; ++rr)
                    s_ep[(it * 16 + quad * 4 + rr) * 516 + w4 * 128 + dt * 16 + l16] =
                        acc[it][dt][rr];
        if (l16 == 0) {
            #pragma unroll
            for (int it = 0; it < 2; ++it)
                #pragma unroll
                for (int rr = 0; rr < 4; ++rr)
                    s_as[w4][it * 16 + quad * 4 + rr] = asum[it][rr];
        }
    }
    __syncthreads();
    if (jh == 0) {
        float rs[2][4];
        #pragma unroll
        for (int it = 0; it < 2; ++it)
            #pragma unroll
            for (int rr = 0; rr < 4; ++rr)
                rs[it][rr] = 1.f / (asum[it][rr] + s_as[w4][it * 16 + quad * 4 + rr]);
        #pragma unroll
        for (int it = 0; it < 2; ++it)
            #pragma unroll
            for (int dt = 0; dt < 8; ++dt)
                #pragma unroll
                for (int rr = 0; rr < 4; ++rr) {
                    int off = (it * 16 + quad * 4 + rr) * 516 + w4 * 128 + dt * 16 + l16;
                    s_ep[off] = (acc[it][dt][rr] + s_ep[off]) * rs[it][rr];
                }
    }
    __syncthreads();

    #pragma unroll
    for (int q = 0; q < 4; ++q) {
        int ir = w * 4 + q;
        int ig = i0 + ir;
        float4 p0 = *(const float4*)(&s_ep[ir * 516 + lane * 8]);
        float4 p1 = *(const float4*)(&s_ep[ir * 516 + lane * 8 + 4]);
        const float* xp = X + (((size_t)((b << 10) + ig)) << 9) + lane * 8;
        float4 x0 = *(const float4*)(xp);
        float4 x1 = *(const float4*)(xp + 4);
        float v[8] = {p0.x + x0.x, p0.y + x0.y, p0.z + x0.z, p0.w + x0.w,
                      p1.x + x1.x, p1.y + x1.y, p1.z + x1.z, p1.w + x1.w};
        float s1 = 0.f, s2 = 0.f;
        #pragma unroll
        for (int u = 0; u < 8; ++u) { s1 += v[u]; s2 += v[u] * v[u]; }
        #pragma unroll
        for (int off = 1; off < 64; off <<= 1) { s1 += __shfl_xor(s1, off); s2 += __shfl_xor(s2, off); }
        float mean = s1 * (1.f / 512.f);
        float var  = s2 * (1.f / 512.f) - mean * mean;
        float rstd = rsqrtf(var + 1e-5f);
        int f0i = lane * 8;
        float4 g0 = *(const float4*)(gamma + f0i);
        float4 g1 = *(const float4*)(gamma + f0i + 4);
        float4 be0 = *(const float4*)(beta + f0i);
        float4 be1 = *(const float4*)(beta + f0i + 4);
        float* op = out + (((size_t)((b << 10) + ig)) << 9) + f0i;
        float4 o0, o1;
        o0.x = (v[0] - mean) * rstd * g0.x + be0.x;
        o0.y = (v[1] - mean) * rstd * g0.y + be0.y;
        o0.z = (v[2] - mean) * rstd * g0.z + be0.z;
        o0.w = (v[3] - mean) * rstd * g0.w + be0.w;
        o1.x = (v[4] - mean) * rstd * g1.x + be1.x;
        o1.y = (v[5] - mean) * rstd * g1.y + be1.y;
        o1.z = (v[6] - mean) * rstd * g1.z + be1.z;
        o1.w = (v[7] - mean) * rstd * g1.w + be1.w;
        *(float4*)op = o0;
        *(float4*)(op + 4) = o1;
    }
}

extern "C" void kernel_launch(void* const* d_in, const int* in_sizes, int n_in,
                              void* d_out, int out_size, void* d_ws, size_t ws_size,
                              hipStream_t stream) {
    const float* x     = (const float*)d_in[0];
    const int*   mask  = (const int*)d_in[1];
    const float* W     = (const float*)d_in[2];
    const float* a_src = (const float*)d_in[3];
    const float* a_dst = (const float*)d_in[4];
    const float* gamma = (const float*)d_in[5];
    const float* beta  = (const float*)d_in[6];
    float* out = (float*)d_out;

    ushort* hT = (ushort*)d_ws;                            // 8 MB
    ushort* Xc = hT + (size_t)8 * 512 * 1024;              // 8 MB
    ushort* Wc = Xc + (size_t)8 * 1024 * 512;              // 0.5 MB
    float* ei = (float*)(Wc + (size_t)512 * 512);          // 128 KB
    float* ej = ei + 32768;

    conv_xw<<<dim3(576), 256, 0, stream>>>(x, W, Xc, Wc);
    gemm_xw<<<dim3(512), 256, 0, stream>>>(Xc, Wc, a_src, a_dst, hT, ei, ej);
    attn_pv<<<dim3(256), 512, 0, stream>>>(hT, ei, ej, mask, x, gamma, beta, out);
}